// Round 2
// baseline (417.369 us; speedup 1.0000x reference)
//
#include <hip/hip_runtime.h>
#include <math.h>

#define N_NODES 50000
#define N_EDGES 800000
#define IN_DIM 128
#define HID 256
#define NCLASS 40

#define SCAN_NBLK 49   // ceil(50000 / 1024)

// CSR build: 256 privatized histogram blocks, 8-bit packed counters (4 rows/u32)
#define HBLK 256
#define EPB  3125      // edges per hist block: 256 * 3125 = 800000 exactly
#define PK   12500     // packed u32 bins (50000 rows / 4)

typedef __attribute__((ext_vector_type(8))) short short8;
typedef __attribute__((ext_vector_type(4))) float floatx4;
typedef __attribute__((ext_vector_type(2))) unsigned uintx2;

// ---------- bf16 helpers (RNE pack, cheap unpack) ----------
__device__ inline unsigned bf16pair(float a, float b) {
    unsigned ua = __float_as_uint(a), ub = __float_as_uint(b);
    ua = (ua + 0x7fffu + ((ua >> 16) & 1u)) >> 16;
    ub = (ub + 0x7fffu + ((ub >> 16) & 1u)) >> 16;
    return ua | (ub << 16);
}
__device__ inline unsigned bf16bits(float a) {
    unsigned ua = __float_as_uint(a);
    return (ua + 0x7fffu + ((ua >> 16) & 1u)) >> 16;
}
__device__ inline float bf_lo(unsigned u) { return __uint_as_float(u << 16); }
__device__ inline float bf_hi(unsigned u) { return __uint_as_float(u & 0xffff0000u); }

// ---------------- prep: feats->bf16 + W1 fragment pack (atomic-free streaming) ----------------
__global__ void prep_kernel(const float4* __restrict__ f4,
                            uint2* __restrict__ fb16,
                            const float* __restrict__ W1,
                            uint4* __restrict__ W1frag) {
    int i = blockIdx.x * blockDim.x + threadIdx.x;   // < 1.6M
    float4 v = f4[i];
    fb16[i] = make_uint2(bf16pair(v.x, v.y), bf16pair(v.z, v.w));
    if (i < 4096) {
        int f = i;
        int h = f >> 11, rem = f & 2047;
        int t = rem >> 8, s = (rem >> 6) & 3, l = rem & 63;
        int q = l >> 4, n16 = l & 15;
        int n = h * 128 + t * 16 + n16;
        int kb = s * 32 + q * 8;
        unsigned p[4];
        #pragma unroll
        for (int jj = 0; jj < 4; ++jj) {
            float a = W1[(size_t)(kb + 2 * jj) * HID + n];
            float b = W1[(size_t)(kb + 2 * jj + 1) * HID + n];
            p[jj] = bf16pair(a, b);
        }
        W1frag[f] = make_uint4(p[0], p[1], p[2], p[3]);
    }
}

// ---------------- hist: per-block privatized LDS histogram, 8-bit packed ----------------
__global__ __launch_bounds__(1024) void hist_kernel(const int* __restrict__ rows,
                                                    unsigned* __restrict__ hist) {
    __shared__ unsigned h[PK];    // 50 KB
    int t = threadIdx.x;
    for (int i = t; i < PK / 4; i += 1024)
        ((uint4*)h)[i] = make_uint4(0u, 0u, 0u, 0u);
    __syncthreads();
    int e0 = blockIdx.x * EPB;
    for (int i = t; i < EPB; i += 1024) {
        int r = rows[e0 + i];
        atomicAdd(&h[r >> 2], 1u << ((r & 3) * 8));   // LDS atomic
    }
    __syncthreads();
    unsigned* out = hist + (size_t)blockIdx.x * PK;
    for (int i = t; i < PK / 4; i += 1024)
        ((uint4*)out)[i] = ((const uint4*)h)[i];
}

// ---------------- colscan: per-row prefix across the 256 block-histograms ----------------
__global__ void colscan_kernel(const unsigned* __restrict__ hist,
                               unsigned* __restrict__ base,
                               int* __restrict__ counts,
                               int* __restrict__ blockSums) {
    int t = blockIdx.x * 256 + threadIdx.x;
    unsigned run = 0;            // 4 packed 8-bit running sums (no byte overflow: degree < 256)
    if (t < PK) {
        #pragma unroll 8
        for (int b = 0; b < HBLK; ++b) {
            unsigned v = hist[b * PK + t];
            base[b * PK + t] = run;
            run += v;
        }
        *(int4*)(counts + 4 * t) = make_int4((int)(run & 0xffu), (int)((run >> 8) & 0xffu),
                                             (int)((run >> 16) & 0xffu), (int)(run >> 24));
    }
    int s = (int)((run & 0xffu) + ((run >> 8) & 0xffu) + ((run >> 16) & 0xffu) + (run >> 24));
    #pragma unroll
    for (int off = 32; off >= 1; off >>= 1)
        s += __shfl_xor(s, off);
    __shared__ int wsum[4];
    int lane = threadIdx.x & 63, wid = threadIdx.x >> 6;
    if (lane == 0) wsum[wid] = s;
    __syncthreads();
    if (threadIdx.x == 0)
        blockSums[blockIdx.x] = wsum[0] + wsum[1] + wsum[2] + wsum[3];
}

// ---------------- local scan (fused block-offset scan) -> row_start ----------------
__global__ void local_scan_kernel(const int* __restrict__ counts,
                                  const int* __restrict__ blockSums,
                                  int* __restrict__ row_start) {
    __shared__ int wsum[4];
    __shared__ int boff;
    int t = threadIdx.x;
    // wave 0: scan the 49 block sums; every block computes its own offset
    if (t < 64) {
        int x = (t < SCAN_NBLK) ? blockSums[t] : 0;
        #pragma unroll
        for (int off = 1; off < 64; off <<= 1) {
            int y = __shfl_up(x, off);
            if (t >= off) x += y;
        }
        int excl = __shfl_up(x, 1);
        if (t == 0) excl = 0;
        if (t == blockIdx.x) boff = excl;
        if (blockIdx.x == SCAN_NBLK - 1 && t == SCAN_NBLK - 1)
            row_start[N_NODES] = x;   // grand total
    }
    int base = blockIdx.x * 1024 + t * 4;
    int4 c = make_int4(0, 0, 0, 0);
    if (base < N_NODES) c = *(const int4*)(counts + base);
    int s0 = c.x, s1 = s0 + c.y, s2 = s1 + c.z, s3 = s2 + c.w;
    int tsum = s3;
    int lane = t & 63, wid = t >> 6;
    int x = tsum;
    #pragma unroll
    for (int off = 1; off < 64; off <<= 1) {
        int y = __shfl_up(x, off);
        if (lane >= off) x += y;
    }
    if (lane == 63) wsum[wid] = x;
    __syncthreads();
    int woff = 0;
    for (int i = 0; i < 4; ++i)
        if (i < wid) woff += wsum[i];
    int excl = x - tsum + woff + boff;
    if (base < N_NODES) {
        int4 rs = make_int4(excl, excl + s0, excl + s1, excl + s2);
        *(int4*)(row_start + base) = rs;
    }
}

// ---------------- scatter2: rank via LDS atomic replay (zero global atomics) ----------------
__global__ __launch_bounds__(1024) void scatter2_kernel(const int* __restrict__ rows,
                                                        const int* __restrict__ cols,
                                                        const float* __restrict__ vals,
                                                        const unsigned* __restrict__ base,
                                                        const int* __restrict__ row_start,
                                                        unsigned* __restrict__ csr_cv) {
    __shared__ unsigned cur[PK];  // 50 KB: this block's packed per-row bases
    int t = threadIdx.x;
    const uint4* bb = (const uint4*)(base + (size_t)blockIdx.x * PK);
    for (int i = t; i < PK / 4; i += 1024)
        ((uint4*)cur)[i] = bb[i];
    __syncthreads();
    int e0 = blockIdx.x * EPB;
    for (int i = t; i < EPB; i += 1024) {
        int e = e0 + i;
        int r = rows[e];
        unsigned sh = (unsigned)(r & 3) * 8u;
        unsigned old = atomicAdd(&cur[r >> 2], 1u << sh);   // LDS atomic
        int pos = row_start[r] + (int)((old >> sh) & 0xffu);
        csr_cv[pos] = ((unsigned)cols[e] << 16) | bf16bits(vals[e]);
    }
}

// ---------------- SpMM (CSR, dim-sliced for L2 residency) ----------------
// grid = (12500, 4): blockIdx.y = 32-dim slice. Per slice the gather working set is
// 50000 rows x 64 B = 3.2 MB -> fits per-XCD 4 MB L2. Linear dispatch order keeps
// slices phase-separated; streaming traffic (csr, outputs, adds) is non-temporal so
// only the gathered Hin slice occupies L2.
// Lane layout: lane = 8p+q. p = edge-of-octet (8 edges per inst), q = dim quad
// (4 bf16 = 8 B). One uintx2 gather per lane touches one 64 B line per edge.
// MODE 0: Hout[r] = bf16(acc)                               (hop 2)
// MODE 1: Hout[r] = bf16(0.5*acc)                           (hop 1, folds input scale)
// MODE 2: Hout[r] = bf16(0.5*feats[r] + h1[r] + h2[r] + acc)   (hop 3, y in bf16)
template <int MODE>
__global__ void spmm_csr(const int* __restrict__ row_start,
                         const unsigned* __restrict__ csr_cv,
                         const uintx2* __restrict__ Hin2,
                         uintx2* __restrict__ Hout2,
                         const float* __restrict__ feats,
                         const uintx2* __restrict__ h1b2,
                         const uintx2* __restrict__ h2b2) {
    int row  = blockIdx.x * 4 + (threadIdx.x >> 6);
    int lane = threadIdx.x & 63;
    int s    = blockIdx.y;          // dim slice, 32 dims
    int p = lane >> 3;              // 0..7: edge-of-octet
    int q = lane & 7;               // 0..7: dim quad (8 B of the 64 B slice row)
    int start = row_start[row];
    int end   = row_start[row + 1];
    float a0 = 0.f, a1 = 0.f, a2 = 0.f, a3 = 0.f;
    for (int base = start; base < end; base += 64) {
        int idx = base + lane;
        unsigned u = 0;                         // col=0, val=+0.0 padding
        if (idx < end) u = __builtin_nontemporal_load(csr_cv + idx);
        int cnt = min(64, end - base);
        for (int j = 0; j < cnt; j += 8) {
            unsigned uj = __shfl(u, j + p);
            int   c = uj >> 16;
            float v = __uint_as_float(uj << 16);
            uintx2 h = Hin2[(size_t)c * 32 + s * 8 + q];   // cached gather (L2-resident slice)
            a0 += v * bf_lo(h.x);
            a1 += v * bf_hi(h.x);
            a2 += v * bf_lo(h.y);
            a3 += v * bf_hi(h.y);
        }
    }
    // reduce the 8 edge-subsets (lane bits 3..5)
    #pragma unroll
    for (int off = 8; off <= 32; off <<= 1) {
        a0 += __shfl_xor(a0, off);
        a1 += __shfl_xor(a1, off);
        a2 += __shfl_xor(a2, off);
        a3 += __shfl_xor(a3, off);
    }
    if (p == 0) {
        size_t o = (size_t)row * 32 + s * 8 + q;
        if (MODE == 1) {
            a0 *= 0.5f; a1 *= 0.5f; a2 *= 0.5f; a3 *= 0.5f;
        } else if (MODE == 2) {
            size_t of = (size_t)row * IN_DIM + s * 32 + q * 4;
            floatx4 f = __builtin_nontemporal_load((const floatx4*)(feats + of));
            uintx2 A = __builtin_nontemporal_load(h1b2 + o);
            uintx2 B = __builtin_nontemporal_load(h2b2 + o);
            a0 += 0.5f * f.x + bf_lo(A.x) + bf_lo(B.x);
            a1 += 0.5f * f.y + bf_hi(A.x) + bf_hi(B.x);
            a2 += 0.5f * f.z + bf_lo(A.y) + bf_lo(B.y);
            a3 += 0.5f * f.w + bf_hi(A.y) + bf_hi(B.y);
        }
        uintx2 r;
        r.x = bf16pair(a0, a1);
        r.y = bf16pair(a2, a3);
        __builtin_nontemporal_store(r, Hout2 + o);
    }
}

// ---------------- GEMM1 (MFMA): H1 = relu(0.25*(ybf16 @ W1) + b1) ----------------
__global__ void gemm1_mfma(const uint4* __restrict__ yb4,
                           const uint4* __restrict__ W1frag,
                           const float* __restrict__ bias1,
                           float* __restrict__ H1) {
    __shared__ uint4 wlds[2048];   // 32 KB: this block's N-half of W1 fragments
    int tid = threadIdx.x;
    int h = blockIdx.y;
    for (int i = tid; i < 2048; i += 256)
        wlds[i] = W1frag[h * 2048 + i];
    __syncthreads();

    int wave = tid >> 6, lane = tid & 63;
    int q = lane >> 4, c16 = lane & 15;
    int row0 = blockIdx.x * 64 + wave * 16;
    int arow = row0 + c16;

    union { uint4 u; short8 v; } au[4], bu;
    if (arow < N_NODES) {
        #pragma unroll
        for (int s = 0; s < 4; ++s)
            au[s].u = yb4[(size_t)arow * 16 + 4 * s + q];
    } else {
        #pragma unroll
        for (int s = 0; s < 4; ++s)
            au[s].u = make_uint4(0u, 0u, 0u, 0u);
    }

    #pragma unroll
    for (int t = 0; t < 8; ++t) {
        floatx4 acc = {0.f, 0.f, 0.f, 0.f};
        #pragma unroll
        for (int s = 0; s < 4; ++s) {
            bu.u = wlds[(t * 4 + s) * 64 + lane];
            acc = __builtin_amdgcn_mfma_f32_16x16x32_bf16(au[s].v, bu.v, acc, 0, 0, 0);
        }
        int col = h * 128 + t * 16 + c16;
        float bs = bias1[col];
        #pragma unroll
        for (int r = 0; r < 4; ++r) {
            int crow = row0 + q * 4 + r;
            if (crow < N_NODES) {
                float v = 0.25f * acc[r] + bs;
                H1[(size_t)crow * HID + col] = v > 0.f ? v : 0.f;
            }
        }
    }
}

// ---------------- GEMM2 (K-split x2): partial = H1[:, khalf] @ W2[khalf, :] ----------------
#define G2_BM 128
#define G2_BK 32
__global__ void gemm2_kernel(const float* __restrict__ H1,
                             const float* __restrict__ W2,
                             float* __restrict__ part0,
                             float* __restrict__ part1) {
    __shared__ float As[G2_BK][G2_BM + 4];   // transposed A
    __shared__ float Bs[G2_BK][44];          // 32 x 40, row pad to 44
    int tid = threadIdx.x;                   // 256
    int rt = tid >> 3;                       // 0..31, 4 rows each
    int ct = tid & 7;                        // 0..7, 5 cols each
    int row0 = blockIdx.x * G2_BM;
    int kbase = blockIdx.y * (HID / 2);      // 0 or 128
    float* outp = blockIdx.y ? part1 : part0;
    float acc[4][5] = {};
    for (int kt = 0; kt < HID / 2; kt += G2_BK) {    // 4 k-tiles
        int k0 = kbase + kt;
        #pragma unroll
        for (int i = tid; i < 1024; i += 256) {
            int r = i >> 3, u = i & 7;
            int gr = row0 + r;
            float4 v = make_float4(0.f, 0.f, 0.f, 0.f);
            if (gr < N_NODES)
                v = *(const float4*)(H1 + (size_t)gr * HID + k0 + u * 4);
            int kb = u * 4;
            As[kb + 0][r] = v.x;
            As[kb + 1][r] = v.y;
            As[kb + 2][r] = v.z;
            As[kb + 3][r] = v.w;
        }
        for (int i = tid; i < 320; i += 256) {
            int r = i / 10, cg = i % 10;
            float4 w = *(const float4*)(W2 + (size_t)(k0 + r) * NCLASS + cg * 4);
            *(float4*)&Bs[r][cg * 4] = w;
        }
        __syncthreads();
        #pragma unroll
        for (int kk = 0; kk < G2_BK; ++kk) {
            float4 a0 = *(const float4*)&As[kk][rt * 4];
            float a[4] = {a0.x, a0.y, a0.z, a0.w};
            float b[5];
            #pragma unroll
            for (int j = 0; j < 5; ++j) b[j] = Bs[kk][ct * 5 + j];
            #pragma unroll
            for (int i = 0; i < 4; ++i)
                #pragma unroll
                for (int j = 0; j < 5; ++j)
                    acc[i][j] += a[i] * b[j];
        }
        __syncthreads();
    }
    #pragma unroll
    for (int i = 0; i < 4; ++i) {
        int gr = row0 + rt * 4 + i;
        if (gr >= N_NODES) continue;
        float* dst = outp + (size_t)gr * NCLASS + ct * 5;
        #pragma unroll
        for (int j = 0; j < 5; ++j)
            dst[j] = acc[i][j];
    }
}

// ---------------- double log_softmax (sums K-split partials + bias) ----------------
__global__ void lsm_kernel(const float* __restrict__ part0,
                           const float* __restrict__ part1,
                           const float* __restrict__ b2,
                           float* __restrict__ Out) {
    int wave = threadIdx.x >> 6;
    int lane = threadIdx.x & 63;
    int row = blockIdx.x * 4 + wave;
    if (row >= N_NODES) return;

    float acc = -INFINITY;
    if (lane < NCLASS) {
        size_t idx = (size_t)row * NCLASS + lane;
        acc = part0[idx] + part1[idx] + b2[lane];
    }

    float m = acc;
    #pragma unroll
    for (int off = 32; off >= 1; off >>= 1)
        m = fmaxf(m, __shfl_xor(m, off));
    float ex = (lane < NCLASS) ? expf(acc - m) : 0.f;
    float s = ex;
    #pragma unroll
    for (int off = 32; off >= 1; off >>= 1)
        s += __shfl_xor(s, off);
    float z1 = acc - (m + logf(s));

    float m2 = z1;
    #pragma unroll
    for (int off = 32; off >= 1; off >>= 1)
        m2 = fmaxf(m2, __shfl_xor(m2, off));
    float ex2 = (lane < NCLASS) ? expf(z1 - m2) : 0.f;
    float s2 = ex2;
    #pragma unroll
    for (int off = 32; off >= 1; off >>= 1)
        s2 += __shfl_xor(s2, off);
    float z2 = z1 - (m2 + logf(s2));

    if (lane < NCLASS)
        Out[(size_t)row * NCLASS + lane] = z2;
}

extern "C" void kernel_launch(void* const* d_in, const int* in_sizes, int n_in,
                              void* d_out, int out_size, void* d_ws, size_t ws_size,
                              hipStream_t stream) {
    const float* feats   = (const float*)d_in[0];
    const int*   e_row   = (const int*)d_in[1];
    const int*   e_col   = (const int*)d_in[2];
    const float* e_vals  = (const float*)d_in[3];
    const float* W1      = (const float*)d_in[4];
    const float* b1      = (const float*)d_in[5];
    const float* W2      = (const float*)d_in[6];
    const float* b2      = (const float*)d_in[7];
    float* out = (float*)d_out;

    // Workspace (19.2M floats proven):
    //   hist  : [0, 3.2M)           256 x 12500 packed u32 (12.8 MB; dead before hop3)
    //   ybf   : [0, 3.2M)           y in bf16 (MLP input, written by hop3)
    //   W1frag: [3.2M, 3.216M)      W1 bf16 MFMA fragments (64 KB)
    //   counts: [3.3M, 3.35M)       per-row degrees (dead after local_scan)
    //   fb16  : [6.4M, 9.6M)        feats in bf16
    //   h1b   : [9.6M, 12.8M)       hop1 out, bf16
    //   h2b   : [12.8M, 16M)        hop2 out, bf16
    //   base  : [16M, 19.2M)        per-(block,row) packed bases (dead after scatter)
    //   hid   : [6.4M, 19.2M)       gemm1 out fp32 (all above dead by then)
    //   part0 : [0, 2M)  part1: [2M, 4M)
    float* ws    = (float*)d_ws;
    uint4* ybf4  = (uint4*)ws;
    unsigned* hist = (unsigned*)ws;
    uint4* W1frag = (uint4*)(ws + (size_t)N_NODES * IN_DIM / 2);
    int*   counts = (int*)(ws + 3300000);
    uint4* fb16_4 = (uint4*)(ws + (size_t)N_NODES * IN_DIM);
    uint4* h1b4  = (uint4*)(ws + (size_t)N_NODES * IN_DIM * 3 / 2);
    uint4* h2b4  = (uint4*)(ws + (size_t)N_NODES * IN_DIM * 2);
    unsigned* basep = (unsigned*)(ws + (size_t)N_NODES * IN_DIM * 5 / 2);   // 16M..19.2M
    float* hid   = ws + (size_t)N_NODES * IN_DIM;
    float* part0 = ws;
    float* part1 = ws + (size_t)N_NODES * NCLASS;

    // CSR scratch in d_out (8 MB; fully overwritten by lsm_kernel at the end).
    unsigned* csr_cv = (unsigned*)d_out;                 // packed (col<<16)|bf16(val), 800000
    int*   row_start = (int*)d_out + 2 * N_EDGES;        // [1600000, 1650001)
    int*   blockSums = row_start + N_NODES + 4;          // < 2000000

    // prep: feats->bf16 + W1 fragment pack (pure streaming, no atomics)
    const int ELEMS4 = N_NODES * IN_DIM / 4;  // 1.6M float4s
    prep_kernel<<<ELEMS4 / 256, 256, 0, stream>>>((const float4*)feats, (uint2*)fb16_4,
                                                  W1, W1frag);

    // CSR build, zero global atomics:
    // privatized LDS histograms -> cross-block column scan -> fused hierarchical row scan
    // -> LDS-replay scatter
    hist_kernel<<<HBLK, 1024, 0, stream>>>(e_row, hist);
    colscan_kernel<<<SCAN_NBLK, 256, 0, stream>>>(hist, basep, counts, blockSums);
    local_scan_kernel<<<SCAN_NBLK, 256, 0, stream>>>(counts, blockSums, row_start);
    scatter2_kernel<<<HBLK, 1024, 0, stream>>>(e_row, e_col, e_vals, basep,
                                               row_start, csr_cv);

    // 3 propagation hops, dim-sliced (grid.y = 4 slices of 32 dims each)
    dim3 spg(N_NODES / 4, 4);                 // (12500, 4)
    spmm_csr<1><<<spg, 256, 0, stream>>>(row_start, csr_cv, (const uintx2*)fb16_4,
                                         (uintx2*)h1b4, nullptr, nullptr, nullptr);
    spmm_csr<0><<<spg, 256, 0, stream>>>(row_start, csr_cv, (const uintx2*)h1b4,
                                         (uintx2*)h2b4, nullptr, nullptr, nullptr);
    spmm_csr<2><<<spg, 256, 0, stream>>>(row_start, csr_cv, (const uintx2*)h2b4,
                                         (uintx2*)ybf4, feats,
                                         (const uintx2*)h1b4, (const uintx2*)h2b4);

    // GEMM1 (MFMA): hid = relu(0.25*(ybf @ W1) + b1)
    dim3 g1((N_NODES + 63) / 64, 2);          // (782, 2)
    gemm1_mfma<<<g1, 256, 0, stream>>>(ybf4, W1frag, b1, hid);

    // GEMM2 (K-split x2): partials into dead y region
    dim3 g2((N_NODES + G2_BM - 1) / G2_BM, 2);        // (391, 2)
    gemm2_kernel<<<g2, 256, 0, stream>>>(hid, W2, part0, part1);

    // double log_softmax (sums partials + bias) -> out
    lsm_kernel<<<(N_NODES + 3) / 4, 256, 0, stream>>>(part0, part1, b2, out);
}

// Round 4
// 268.860 us; speedup vs baseline: 1.5524x; 1.5524x over previous
//
#include <hip/hip_runtime.h>
#include <math.h>

#define N_NODES 50000
#define N_EDGES 800000
#define IN_DIM 128
#define HID 256
#define NCLASS 40

#define SCAN_NBLK 49   // ceil(50000 / 1024)

// CSR build: 256 privatized histogram blocks, 8-bit packed counters (4 rows/u32)
#define HBLK 256
#define EPB  3125      // edges per hist block: 256 * 3125 = 800000 exactly
#define PK   12500     // packed u32 bins (50000 rows / 4)
#define CS_G 4         // colscan hist groups
#define CS_HPG 64      // hists per group (256/4)

typedef __attribute__((ext_vector_type(8))) short short8;
typedef __attribute__((ext_vector_type(4))) float floatx4;
typedef __attribute__((ext_vector_type(4))) unsigned uintx4;

// ---------- bf16 helpers (RNE pack, cheap unpack) ----------
__device__ inline unsigned bf16pair(float a, float b) {
    unsigned ua = __float_as_uint(a), ub = __float_as_uint(b);
    ua = (ua + 0x7fffu + ((ua >> 16) & 1u)) >> 16;
    ub = (ub + 0x7fffu + ((ub >> 16) & 1u)) >> 16;
    return ua | (ub << 16);
}
__device__ inline unsigned bf16bits(float a) {
    unsigned ua = __float_as_uint(a);
    return (ua + 0x7fffu + ((ua >> 16) & 1u)) >> 16;
}
__device__ inline float bf_lo(unsigned u) { return __uint_as_float(u << 16); }
__device__ inline float bf_hi(unsigned u) { return __uint_as_float(u & 0xffff0000u); }

// ---------------- prep: feats->bf16 + W1 fragment pack (atomic-free streaming) ----------------
__global__ void prep_kernel(const float4* __restrict__ f4,
                            uint2* __restrict__ fb16,
                            const float* __restrict__ W1,
                            uint4* __restrict__ W1frag) {
    int i = blockIdx.x * blockDim.x + threadIdx.x;   // < 1.6M
    float4 v = f4[i];
    fb16[i] = make_uint2(bf16pair(v.x, v.y), bf16pair(v.z, v.w));
    if (i < 4096) {
        int f = i;
        int h = f >> 11, rem = f & 2047;
        int t = rem >> 8, s = (rem >> 6) & 3, l = rem & 63;
        int q = l >> 4, n16 = l & 15;
        int n = h * 128 + t * 16 + n16;
        int kb = s * 32 + q * 8;
        unsigned p[4];
        #pragma unroll
        for (int jj = 0; jj < 4; ++jj) {
            float a = W1[(size_t)(kb + 2 * jj) * HID + n];
            float b = W1[(size_t)(kb + 2 * jj + 1) * HID + n];
            p[jj] = bf16pair(a, b);
        }
        W1frag[f] = make_uint4(p[0], p[1], p[2], p[3]);
    }
}

// ---------------- hist: per-block privatized LDS histogram, 8-bit packed ----------------
__global__ __launch_bounds__(1024) void hist_kernel(const int* __restrict__ rows,
                                                    unsigned* __restrict__ hist) {
    __shared__ unsigned h[PK];    // 50 KB
    int t = threadIdx.x;
    for (int i = t; i < PK / 4; i += 1024)
        ((uint4*)h)[i] = make_uint4(0u, 0u, 0u, 0u);
    __syncthreads();
    int e0 = blockIdx.x * EPB;
    for (int i = t; i < EPB; i += 1024) {
        int r = rows[e0 + i];
        atomicAdd(&h[r >> 2], 1u << ((r & 3) * 8));   // LDS atomic
    }
    __syncthreads();
    unsigned* out = hist + (size_t)blockIdx.x * PK;
    for (int i = t; i < PK / 4; i += 1024)
        ((uint4*)out)[i] = ((const uint4*)h)[i];
}

// ---------------- colscan v2: 4-way parallel per-row prefix across 256 block-histograms ----
// Thread (g, c) serially scans hists [g*64, g*64+64) for column-quad colq, writing
// group-local bases. Cross-group offsets resolved via LDS into goff[g][colq] (byte-packed,
// added by scatter2). Also emits per-scanblock row sums (block == scan-block: 1024 rows).
__global__ __launch_bounds__(1024) void colscan_kernel(const unsigned* __restrict__ hist,
                                                       unsigned* __restrict__ base,
                                                       unsigned* __restrict__ goff,
                                                       int* __restrict__ counts,
                                                       int* __restrict__ blockSums) {
    __shared__ unsigned lsum[CS_G][256];
    int tid = threadIdx.x;          // 1024
    int g = tid >> 8;               // 0..3 hist group
    int c = tid & 255;              // col-quad within block
    int colq = blockIdx.x * 256 + c;
    unsigned run = 0;               // 4 packed 8-bit running sums (degree < 256: no overflow)
    if (colq < PK) {
        #pragma unroll 8
        for (int i = 0; i < CS_HPG; ++i) {
            int b = g * CS_HPG + i;
            unsigned v = hist[(size_t)b * PK + colq];
            base[(size_t)b * PK + colq] = run;
            run += v;
        }
    }
    lsum[g][c] = run;
    __syncthreads();
    unsigned off = 0;
    #pragma unroll
    for (int gg = 0; gg < CS_G; ++gg) {
        unsigned v = lsum[gg][c];
        if (gg < g) off += v;
    }
    unsigned tot = off + run;       // valid for g == CS_G-1: full per-row degrees (packed)
    if (colq < PK) {
        goff[(size_t)g * PK + colq] = off;
        if (g == CS_G - 1)
            *(int4*)(counts + 4 * colq) = make_int4((int)(tot & 0xffu), (int)((tot >> 8) & 0xffu),
                                                    (int)((tot >> 16) & 0xffu), (int)(tot >> 24));
    }
    // per-scanblock edge-count sum (rows [blk*1024, blk*1024+1024))
    int s = 0;
    if (g == CS_G - 1 && colq < PK)
        s = (int)((tot & 0xffu) + ((tot >> 8) & 0xffu) + ((tot >> 16) & 0xffu) + (tot >> 24));
    #pragma unroll
    for (int o = 32; o >= 1; o >>= 1)
        s += __shfl_xor(s, o);
    __shared__ int wsum[16];
    int lane = tid & 63, wid = tid >> 6;
    if (lane == 0) wsum[wid] = s;
    __syncthreads();
    if (tid == 0) {
        int acc = 0;
        #pragma unroll
        for (int i = 0; i < 16; ++i) acc += wsum[i];
        blockSums[blockIdx.x] = acc;
    }
}

// ---------------- local scan (fused block-offset scan) -> row_start ----------------
// NOTE: 256 threads exactly (t*4 covers this block's 1024 rows; wsum sized for 4 waves).
__global__ __launch_bounds__(256) void local_scan_kernel(const int* __restrict__ counts,
                                                         const int* __restrict__ blockSums,
                                                         int* __restrict__ row_start) {
    __shared__ int wsum[4];
    __shared__ int boff;
    int t = threadIdx.x;
    // wave 0: scan the 49 block sums; every block computes its own offset
    if (t < 64) {
        int x = (t < SCAN_NBLK) ? blockSums[t] : 0;
        #pragma unroll
        for (int off = 1; off < 64; off <<= 1) {
            int y = __shfl_up(x, off);
            if (t >= off) x += y;
        }
        int excl = __shfl_up(x, 1);
        if (t == 0) excl = 0;
        if (t == blockIdx.x) boff = excl;
        if (blockIdx.x == SCAN_NBLK - 1 && t == SCAN_NBLK - 1)
            row_start[N_NODES] = x;   // grand total
    }
    int base = blockIdx.x * 1024 + t * 4;
    int4 c = make_int4(0, 0, 0, 0);
    if (base < N_NODES) c = *(const int4*)(counts + base);
    int s0 = c.x, s1 = s0 + c.y, s2 = s1 + c.z, s3 = s2 + c.w;
    int tsum = s3;
    int lane = t & 63, wid = t >> 6;
    int x = tsum;
    #pragma unroll
    for (int off = 1; off < 64; off <<= 1) {
        int y = __shfl_up(x, off);
        if (lane >= off) x += y;
    }
    if (lane == 63) wsum[wid] = x;
    __syncthreads();
    int woff = 0;
    for (int i = 0; i < 4; ++i)
        if (i < wid) woff += wsum[i];
    int excl = x - tsum + woff + boff;
    if (base < N_NODES) {
        int4 rs = make_int4(excl, excl + s0, excl + s1, excl + s2);
        *(int4*)(row_start + base) = rs;
    }
}

// ---------------- scatter2: rank via LDS atomic replay (zero global atomics) ----------------
__global__ __launch_bounds__(1024) void scatter2_kernel(const int* __restrict__ rows,
                                                        const int* __restrict__ cols,
                                                        const float* __restrict__ vals,
                                                        const unsigned* __restrict__ base,
                                                        const unsigned* __restrict__ goff,
                                                        const int* __restrict__ row_start,
                                                        unsigned* __restrict__ csr_cv) {
    __shared__ unsigned cur[PK];  // 50 KB: this block's packed per-row bases
    int t = threadIdx.x;
    const uint4* bb = (const uint4*)(base + (size_t)blockIdx.x * PK);
    const uint4* gg = (const uint4*)(goff + (size_t)(blockIdx.x >> 6) * PK);
    for (int i = t; i < PK / 4; i += 1024) {
        uint4 b = bb[i], o = gg[i];
        // byte-parallel add: per-row sums < 256 so no cross-byte carries
        ((uint4*)cur)[i] = make_uint4(b.x + o.x, b.y + o.y, b.z + o.z, b.w + o.w);
    }
    __syncthreads();
    int e0 = blockIdx.x * EPB;
    for (int i = t; i < EPB; i += 1024) {
        int e = e0 + i;
        int r = rows[e];
        unsigned sh = (unsigned)(r & 3) * 8u;
        unsigned old = atomicAdd(&cur[r >> 2], 1u << sh);   // LDS atomic
        int pos = row_start[r] + (int)((old >> sh) & 0xffu);
        csr_cv[pos] = ((unsigned)cols[e] << 16) | bf16bits(vals[e]);
    }
}

// ---------------- SpMM (CSR, quarter-wave per edge, 16-edge unrolled gathers) ----------------
// lane = 16p+q: p = edge-of-quad, q = dim group of 8 (one 16B chunk of the row).
// Inner loop handles 16 edges (4 quads) per iteration: FOUR independent dwordx4
// gathers in flight per lane (MLP=4). Zero-padding beyond cnt (u=0 -> col 0, val +0.0)
// makes over-run exact; pad gathers broadcast row 0 (L1 hit).
// MODE 0: Hout[r] = bf16(acc)                               (hop 2)
// MODE 1: Hout[r] = bf16(0.5*acc)                           (hop 1, folds input scale)
// MODE 2: Hout[r] = bf16(0.5*feats[r] + h1[r] + h2[r] + acc)   (hop 3, y in bf16)
template <int MODE>
__global__ void spmm_csr(const int* __restrict__ row_start,
                         const unsigned* __restrict__ csr_cv,
                         const uintx4* __restrict__ Hin4,
                         uintx4* __restrict__ Hout4,
                         const float* __restrict__ feats,
                         const uintx4* __restrict__ h1b4,
                         const uintx4* __restrict__ h2b4) {
    int wave = (blockIdx.x * blockDim.x + threadIdx.x) >> 6;
    int lane = threadIdx.x & 63;
    if (wave >= N_NODES) return;
    int p = lane >> 4;          // 0..3: which edge of the quad
    int q = lane & 15;          // dim group (8 dims = 16 B)
    int start = row_start[wave];
    int end   = row_start[wave + 1];
    float acc[8] = {};
    for (int base = start; base < end; base += 64) {
        int idx = base + lane;
        unsigned u = 0;                         // col=0, val=+0.0 padding
        if (idx < end) u = __builtin_nontemporal_load(csr_cv + idx);
        int cnt = min(64, end - base);
        for (int j = 0; j < cnt; j += 16) {
            unsigned uj0 = __shfl(u, j + p);
            unsigned uj1 = __shfl(u, j + 4 + p);
            unsigned uj2 = __shfl(u, j + 8 + p);
            unsigned uj3 = __shfl(u, j + 12 + p);   // <= 63: ok
            int c0 = uj0 >> 16, c1 = uj1 >> 16, c2 = uj2 >> 16, c3 = uj3 >> 16;
            float v0 = __uint_as_float(uj0 << 16);
            float v1 = __uint_as_float(uj1 << 16);
            float v2 = __uint_as_float(uj2 << 16);
            float v3 = __uint_as_float(uj3 << 16);
            uintx4 h0 = Hin4[(size_t)c0 * 16 + q];   // 4 independent gathers in flight
            uintx4 h1 = Hin4[(size_t)c1 * 16 + q];
            uintx4 h2 = Hin4[(size_t)c2 * 16 + q];
            uintx4 h3 = Hin4[(size_t)c3 * 16 + q];
            acc[0] += v0 * bf_lo(h0.x); acc[1] += v0 * bf_hi(h0.x);
            acc[2] += v0 * bf_lo(h0.y); acc[3] += v0 * bf_hi(h0.y);
            acc[4] += v0 * bf_lo(h0.z); acc[5] += v0 * bf_hi(h0.z);
            acc[6] += v0 * bf_lo(h0.w); acc[7] += v0 * bf_hi(h0.w);
            acc[0] += v1 * bf_lo(h1.x); acc[1] += v1 * bf_hi(h1.x);
            acc[2] += v1 * bf_lo(h1.y); acc[3] += v1 * bf_hi(h1.y);
            acc[4] += v1 * bf_lo(h1.z); acc[5] += v1 * bf_hi(h1.z);
            acc[6] += v1 * bf_lo(h1.w); acc[7] += v1 * bf_hi(h1.w);
            acc[0] += v2 * bf_lo(h2.x); acc[1] += v2 * bf_hi(h2.x);
            acc[2] += v2 * bf_lo(h2.y); acc[3] += v2 * bf_hi(h2.y);
            acc[4] += v2 * bf_lo(h2.z); acc[5] += v2 * bf_hi(h2.z);
            acc[6] += v2 * bf_lo(h2.w); acc[7] += v2 * bf_hi(h2.w);
            acc[0] += v3 * bf_lo(h3.x); acc[1] += v3 * bf_hi(h3.x);
            acc[2] += v3 * bf_lo(h3.y); acc[3] += v3 * bf_hi(h3.y);
            acc[4] += v3 * bf_lo(h3.z); acc[5] += v3 * bf_hi(h3.z);
            acc[6] += v3 * bf_lo(h3.w); acc[7] += v3 * bf_hi(h3.w);
        }
    }
    // reduce the 4 edge-subsets (lane bits 4..5)
    #pragma unroll
    for (int i = 0; i < 8; ++i) {
        acc[i] += __shfl_xor(acc[i], 16);
        acc[i] += __shfl_xor(acc[i], 32);
    }
    if (p == 0) {
        size_t o16 = (size_t)wave * 16 + q;
        if (MODE == 1) {
            #pragma unroll
            for (int i = 0; i < 8; ++i) acc[i] *= 0.5f;
        } else if (MODE == 2) {
            size_t of = (size_t)wave * IN_DIM + q * 8;
            floatx4 f0 = __builtin_nontemporal_load((const floatx4*)(feats + of));
            floatx4 f1 = __builtin_nontemporal_load((const floatx4*)(feats + of + 4));
            uintx4 a = __builtin_nontemporal_load(h1b4 + o16);
            uintx4 b = __builtin_nontemporal_load(h2b4 + o16);
            acc[0] += 0.5f * f0.x + bf_lo(a.x) + bf_lo(b.x);
            acc[1] += 0.5f * f0.y + bf_hi(a.x) + bf_hi(b.x);
            acc[2] += 0.5f * f0.z + bf_lo(a.y) + bf_lo(b.y);
            acc[3] += 0.5f * f0.w + bf_hi(a.y) + bf_hi(b.y);
            acc[4] += 0.5f * f1.x + bf_lo(a.z) + bf_lo(b.z);
            acc[5] += 0.5f * f1.y + bf_hi(a.z) + bf_hi(b.z);
            acc[6] += 0.5f * f1.z + bf_lo(a.w) + bf_lo(b.w);
            acc[7] += 0.5f * f1.w + bf_hi(a.w) + bf_hi(b.w);
        }
        uintx4 rv;
        rv.x = bf16pair(acc[0], acc[1]);
        rv.y = bf16pair(acc[2], acc[3]);
        rv.z = bf16pair(acc[4], acc[5]);
        rv.w = bf16pair(acc[6], acc[7]);
        __builtin_nontemporal_store(rv, Hout4 + o16);
    }
}

// ---------------- GEMM1 (MFMA): H1 = relu(0.25*(ybf16 @ W1) + b1) ----------------
__global__ void gemm1_mfma(const uint4* __restrict__ yb4,
                           const uint4* __restrict__ W1frag,
                           const float* __restrict__ bias1,
                           float* __restrict__ H1) {
    __shared__ uint4 wlds[2048];   // 32 KB: this block's N-half of W1 fragments
    int tid = threadIdx.x;
    int h = blockIdx.y;
    for (int i = tid; i < 2048; i += 256)
        wlds[i] = W1frag[h * 2048 + i];
    __syncthreads();

    int wave = tid >> 6, lane = tid & 63;
    int q = lane >> 4, c16 = lane & 15;
    int row0 = blockIdx.x * 64 + wave * 16;
    int arow = row0 + c16;

    union { uint4 u; short8 v; } au[4], bu;
    if (arow < N_NODES) {
        #pragma unroll
        for (int s = 0; s < 4; ++s)
            au[s].u = yb4[(size_t)arow * 16 + 4 * s + q];
    } else {
        #pragma unroll
        for (int s = 0; s < 4; ++s)
            au[s].u = make_uint4(0u, 0u, 0u, 0u);
    }

    #pragma unroll
    for (int t = 0; t < 8; ++t) {
        floatx4 acc = {0.f, 0.f, 0.f, 0.f};
        #pragma unroll
        for (int s = 0; s < 4; ++s) {
            bu.u = wlds[(t * 4 + s) * 64 + lane];
            acc = __builtin_amdgcn_mfma_f32_16x16x32_bf16(au[s].v, bu.v, acc, 0, 0, 0);
        }
        int col = h * 128 + t * 16 + c16;
        float bs = bias1[col];
        #pragma unroll
        for (int r = 0; r < 4; ++r) {
            int crow = row0 + q * 4 + r;
            if (crow < N_NODES) {
                float v = 0.25f * acc[r] + bs;
                H1[(size_t)crow * HID + col] = v > 0.f ? v : 0.f;
            }
        }
    }
}

// ---------------- GEMM2 + double log_softmax (fused, full K per block) ----------------
#define G2_BM 128
__global__ void gemm2lsm_kernel(const float* __restrict__ H1,
                                const float* __restrict__ W2,
                                const float* __restrict__ b2,
                                float* __restrict__ Out) {
    __shared__ float As[32][G2_BM + 4];   // transposed A k-tile
    __shared__ float Bs[32][44];          // 32 x 40, row pad to 44
    int tid = threadIdx.x;                // 256
    int rt = tid >> 3;                    // 0..31, 4 rows each
    int ct = tid & 7;                     // 0..7, 5 cols each
    int row0 = blockIdx.x * G2_BM;
    float acc[4][5] = {};
    for (int k0 = 0; k0 < HID; k0 += 32) {    // 8 k-tiles
        #pragma unroll
        for (int i = tid; i < 1024; i += 256) {
            int r = i >> 3, u = i & 7;
            int gr = row0 + r;
            float4 v = make_float4(0.f, 0.f, 0.f, 0.f);
            if (gr < N_NODES)
                v = *(const float4*)(H1 + (size_t)gr * HID + k0 + u * 4);
            int kb = u * 4;
            As[kb + 0][r] = v.x;
            As[kb + 1][r] = v.y;
            As[kb + 2][r] = v.z;
            As[kb + 3][r] = v.w;
        }
        for (int i = tid; i < 320; i += 256) {
            int r = i / 10, cg = i % 10;
            float4 w = *(const float4*)(W2 + (size_t)(k0 + r) * NCLASS + cg * 4);
            *(float4*)&Bs[r][cg * 4] = w;
        }
        __syncthreads();
        #pragma unroll
        for (int kk = 0; kk < 32; ++kk) {
            float4 a0 = *(const float4*)&As[kk][rt * 4];
            float a[4] = {a0.x, a0.y, a0.z, a0.w};
            float b[5];
            #pragma unroll
            for (int j = 0; j < 5; ++j) b[j] = Bs[kk][ct * 5 + j];
            #pragma unroll
            for (int i = 0; i < 4; ++i)
                #pragma unroll
                for (int j = 0; j < 5; ++j)
                    acc[i][j] += a[i] * b[j];
        }
        __syncthreads();
    }
    // epilogue: + b2, double log_softmax per row (8-lane shuffle groups), write out
    float bb[5];
    #pragma unroll
    for (int j = 0; j < 5; ++j) bb[j] = b2[ct * 5 + j];
    #pragma unroll
    for (int i = 0; i < 4; ++i) {
        int gr = row0 + rt * 4 + i;
        float z[5];
        #pragma unroll
        for (int j = 0; j < 5; ++j) z[j] = acc[i][j] + bb[j];
        float m = z[0];
        #pragma unroll
        for (int j = 1; j < 5; ++j) m = fmaxf(m, z[j]);
        #pragma unroll
        for (int off = 1; off < 8; off <<= 1) m = fmaxf(m, __shfl_xor(m, off));
        float s = 0.f;
        #pragma unroll
        for (int j = 0; j < 5; ++j) s += expf(z[j] - m);
        #pragma unroll
        for (int off = 1; off < 8; off <<= 1) s += __shfl_xor(s, off);
        float l1 = m + logf(s);
        #pragma unroll
        for (int j = 0; j < 5; ++j) z[j] -= l1;
        float m2 = z[0];
        #pragma unroll
        for (int j = 1; j < 5; ++j) m2 = fmaxf(m2, z[j]);
        #pragma unroll
        for (int off = 1; off < 8; off <<= 1) m2 = fmaxf(m2, __shfl_xor(m2, off));
        float s2 = 0.f;
        #pragma unroll
        for (int j = 0; j < 5; ++j) s2 += expf(z[j] - m2);
        #pragma unroll
        for (int off = 1; off < 8; off <<= 1) s2 += __shfl_xor(s2, off);
        float l2 = m2 + logf(s2);
        if (gr < N_NODES) {
            float* dst = Out + (size_t)gr * NCLASS + ct * 5;
            #pragma unroll
            for (int j = 0; j < 5; ++j) dst[j] = z[j] - l2;
        }
    }
}

extern "C" void kernel_launch(void* const* d_in, const int* in_sizes, int n_in,
                              void* d_out, int out_size, void* d_ws, size_t ws_size,
                              hipStream_t stream) {
    const float* feats   = (const float*)d_in[0];
    const int*   e_row   = (const int*)d_in[1];
    const int*   e_col   = (const int*)d_in[2];
    const float* e_vals  = (const float*)d_in[3];
    const float* W1      = (const float*)d_in[4];
    const float* b1      = (const float*)d_in[5];
    const float* W2      = (const float*)d_in[6];
    const float* b2      = (const float*)d_in[7];
    float* out = (float*)d_out;

    // Workspace (19.2M floats proven):
    //   hist  : [0, 3.2M)           256 x 12500 packed u32 (12.8 MB; dead after colscan)
    //   ybf   : [0, 3.2M)           y in bf16 (MLP input, written by hop3)
    //   W1frag: [3.2M, 3.216M)      W1 bf16 MFMA fragments (64 KB)
    //   counts: [3.3M, 3.35M)       per-row degrees (dead after local_scan)
    //   goff  : [3.4M, 3.45M)       colscan group offsets (dead after scatter)
    //   fb16  : [6.4M, 9.6M)        feats in bf16
    //   h1b   : [9.6M, 12.8M)       hop1 out, bf16
    //   h2b   : [12.8M, 16M)        hop2 out, bf16
    //   base  : [16M, 19.2M)        per-(block,row) packed bases (dead after scatter)
    //   hid   : [6.4M, 19.2M)       gemm1 out fp32 (all above dead by then)
    float* ws    = (float*)d_ws;
    uint4* ybf4  = (uint4*)ws;
    unsigned* hist = (unsigned*)ws;
    uint4* W1frag = (uint4*)(ws + (size_t)N_NODES * IN_DIM / 2);
    int*   counts = (int*)(ws + 3300000);
    unsigned* goff = (unsigned*)(ws + 3400000);
    uint4* fb16_4 = (uint4*)(ws + (size_t)N_NODES * IN_DIM);
    uint4* h1b4  = (uint4*)(ws + (size_t)N_NODES * IN_DIM * 3 / 2);
    uint4* h2b4  = (uint4*)(ws + (size_t)N_NODES * IN_DIM * 2);
    unsigned* basep = (unsigned*)(ws + (size_t)N_NODES * IN_DIM * 5 / 2);   // 16M..19.2M
    float* hid   = ws + (size_t)N_NODES * IN_DIM;

    // CSR scratch in d_out (8 MB; fully overwritten by gemm2lsm at the end).
    unsigned* csr_cv = (unsigned*)d_out;                 // packed (col<<16)|bf16(val), 800000
    int*   row_start = (int*)d_out + 2 * N_EDGES;        // [1600000, 1650001)
    int*   blockSums = row_start + N_NODES + 4;          // < 2000000

    // prep: feats->bf16 + W1 fragment pack (pure streaming, no atomics)
    const int ELEMS4 = N_NODES * IN_DIM / 4;  // 1.6M float4s
    prep_kernel<<<ELEMS4 / 256, 256, 0, stream>>>((const float4*)feats, (uint2*)fb16_4,
                                                  W1, W1frag);

    // CSR build, zero global atomics:
    // privatized LDS histograms -> 4-way parallel column scan -> fused hierarchical row scan
    // -> LDS-replay scatter (byte-parallel base+goff)
    hist_kernel<<<HBLK, 1024, 0, stream>>>(e_row, hist);
    colscan_kernel<<<SCAN_NBLK, 1024, 0, stream>>>(hist, basep, goff, counts, blockSums);
    local_scan_kernel<<<SCAN_NBLK, 256, 0, stream>>>(counts, blockSums, row_start);
    scatter2_kernel<<<HBLK, 1024, 0, stream>>>(e_row, e_col, e_vals, basep, goff,
                                               row_start, csr_cv);

    // 3 propagation hops (quarter-wave per edge, 16-edge unrolled: 4 gathers in flight)
    const int SPMM_BLOCKS = N_NODES / 4;      // 12500 (4 waves/block)
    spmm_csr<1><<<SPMM_BLOCKS, 256, 0, stream>>>(row_start, csr_cv, (const uintx4*)fb16_4,
                                                 (uintx4*)h1b4, nullptr, nullptr, nullptr);
    spmm_csr<0><<<SPMM_BLOCKS, 256, 0, stream>>>(row_start, csr_cv, (const uintx4*)h1b4,
                                                 (uintx4*)h2b4, nullptr, nullptr, nullptr);
    spmm_csr<2><<<SPMM_BLOCKS, 256, 0, stream>>>(row_start, csr_cv, (const uintx4*)h2b4,
                                                 (uintx4*)ybf4, feats,
                                                 (const uintx4*)h1b4, (const uintx4*)h2b4);

    // GEMM1 (MFMA): hid = relu(0.25*(ybf @ W1) + b1)
    dim3 g1((N_NODES + 63) / 64, 2);          // (782, 2)
    gemm1_mfma<<<g1, 256, 0, stream>>>(ybf4, W1frag, b1, hid);

    // GEMM2 + double log_softmax (fused) -> out
    gemm2lsm_kernel<<<(N_NODES + G2_BM - 1) / G2_BM, 256, 0, stream>>>(hid, W2, b2, out);
}

// Round 5
// 234.575 us; speedup vs baseline: 1.7793x; 1.1462x over previous
//
#include <hip/hip_runtime.h>
#include <math.h>

#define N_NODES 50000
#define N_EDGES 800000
#define IN_DIM 128
#define HID 256
#define NCLASS 40

#define SCAN_NBLK 49   // ceil(50000 / 1024)

// CSR build: 256 privatized histogram blocks, 8-bit packed counters (4 rows/u32)
#define HBLK 256
#define EPB  3125      // edges per hist block: 256 * 3125 = 800000 exactly
#define PK   12500     // packed u32 bins (50000 rows / 4)
#define CS_G 4         // colscan hist groups
#define CS_HPG 64      // hists per group (256/4)

typedef __attribute__((ext_vector_type(8))) short short8;
typedef __attribute__((ext_vector_type(4))) float floatx4;
typedef __attribute__((ext_vector_type(4))) unsigned uintx4;

// ---------- bf16 helpers (RNE pack, cheap unpack) ----------
__device__ inline unsigned bf16pair(float a, float b) {
    unsigned ua = __float_as_uint(a), ub = __float_as_uint(b);
    ua = (ua + 0x7fffu + ((ua >> 16) & 1u)) >> 16;
    ub = (ub + 0x7fffu + ((ub >> 16) & 1u)) >> 16;
    return ua | (ub << 16);
}
__device__ inline unsigned bf16bits(float a) {
    unsigned ua = __float_as_uint(a);
    return (ua + 0x7fffu + ((ua >> 16) & 1u)) >> 16;
}
__device__ inline float bf_lo(unsigned u) { return __uint_as_float(u << 16); }
__device__ inline float bf_hi(unsigned u) { return __uint_as_float(u & 0xffff0000u); }

// ---------------- prep: feats->bf16 + W1/W2 fragment pack (atomic-free streaming) -------------
__global__ void prep_kernel(const float4* __restrict__ f4,
                            uint2* __restrict__ fb16,
                            const float* __restrict__ W1,
                            uint4* __restrict__ W1frag,
                            const float* __restrict__ W2,
                            uint4* __restrict__ W2frag) {
    int i = blockIdx.x * blockDim.x + threadIdx.x;   // < 1.6M
    float4 v = f4[i];
    fb16[i] = make_uint2(bf16pair(v.x, v.y), bf16pair(v.z, v.w));
    if (i < 4096) {
        int f = i;
        int h = f >> 11, rem = f & 2047;
        int t = rem >> 8, s = (rem >> 6) & 3, l = rem & 63;
        int q = l >> 4, n16 = l & 15;
        int n = h * 128 + t * 16 + n16;
        int kb = s * 32 + q * 8;
        unsigned p[4];
        #pragma unroll
        for (int jj = 0; jj < 4; ++jj) {
            float a = W1[(size_t)(kb + 2 * jj) * HID + n];
            float b = W1[(size_t)(kb + 2 * jj + 1) * HID + n];
            p[jj] = bf16pair(a, b);
        }
        W1frag[f] = make_uint4(p[0], p[1], p[2], p[3]);
    } else if (i < 4096 + 1536) {
        // W2 B-fragments: [nt(3)][ks(8)][lane(64)], cols padded 40->48 with zeros
        int f2 = i - 4096;
        int nt = f2 >> 9;           // /512
        int rem = f2 & 511;
        int ks = rem >> 6, l = rem & 63;
        int col = nt * 16 + (l & 15);
        int k = ks * 32 + (l >> 4) * 8;
        unsigned p[4];
        #pragma unroll
        for (int jj = 0; jj < 4; ++jj) {
            float a = (col < NCLASS) ? W2[(size_t)(k + 2 * jj) * NCLASS + col] : 0.f;
            float b = (col < NCLASS) ? W2[(size_t)(k + 2 * jj + 1) * NCLASS + col] : 0.f;
            p[jj] = bf16pair(a, b);
        }
        W2frag[f2] = make_uint4(p[0], p[1], p[2], p[3]);
    }
}

// ---------------- hist: per-block privatized LDS histogram, 8-bit packed ----------------
__global__ __launch_bounds__(1024) void hist_kernel(const int* __restrict__ rows,
                                                    unsigned* __restrict__ hist) {
    __shared__ unsigned h[PK];    // 50 KB
    int t = threadIdx.x;
    for (int i = t; i < PK / 4; i += 1024)
        ((uint4*)h)[i] = make_uint4(0u, 0u, 0u, 0u);
    __syncthreads();
    int e0 = blockIdx.x * EPB;
    for (int i = t; i < EPB; i += 1024) {
        int r = rows[e0 + i];
        atomicAdd(&h[r >> 2], 1u << ((r & 3) * 8));   // LDS atomic
    }
    __syncthreads();
    unsigned* out = hist + (size_t)blockIdx.x * PK;
    for (int i = t; i < PK / 4; i += 1024)
        ((uint4*)out)[i] = ((const uint4*)h)[i];
}

// ---------------- colscan v2: 4-way parallel per-row prefix across 256 block-histograms ----
__global__ __launch_bounds__(1024) void colscan_kernel(const unsigned* __restrict__ hist,
                                                       unsigned* __restrict__ base,
                                                       unsigned* __restrict__ goff,
                                                       int* __restrict__ counts,
                                                       int* __restrict__ blockSums) {
    __shared__ unsigned lsum[CS_G][256];
    int tid = threadIdx.x;          // 1024
    int g = tid >> 8;               // 0..3 hist group
    int c = tid & 255;              // col-quad within block
    int colq = blockIdx.x * 256 + c;
    unsigned run = 0;               // 4 packed 8-bit running sums (degree < 256: no overflow)
    if (colq < PK) {
        #pragma unroll 8
        for (int i = 0; i < CS_HPG; ++i) {
            int b = g * CS_HPG + i;
            unsigned v = hist[(size_t)b * PK + colq];
            base[(size_t)b * PK + colq] = run;
            run += v;
        }
    }
    lsum[g][c] = run;
    __syncthreads();
    unsigned off = 0;
    #pragma unroll
    for (int gg = 0; gg < CS_G; ++gg) {
        unsigned v = lsum[gg][c];
        if (gg < g) off += v;
    }
    unsigned tot = off + run;       // valid for g == CS_G-1: full per-row degrees (packed)
    if (colq < PK) {
        goff[(size_t)g * PK + colq] = off;
        if (g == CS_G - 1)
            *(int4*)(counts + 4 * colq) = make_int4((int)(tot & 0xffu), (int)((tot >> 8) & 0xffu),
                                                    (int)((tot >> 16) & 0xffu), (int)(tot >> 24));
    }
    // per-scanblock edge-count sum (rows [blk*1024, blk*1024+1024))
    int s = 0;
    if (g == CS_G - 1 && colq < PK)
        s = (int)((tot & 0xffu) + ((tot >> 8) & 0xffu) + ((tot >> 16) & 0xffu) + (tot >> 24));
    #pragma unroll
    for (int o = 32; o >= 1; o >>= 1)
        s += __shfl_xor(s, o);
    __shared__ int wsum[16];
    int lane = tid & 63, wid = tid >> 6;
    if (lane == 0) wsum[wid] = s;
    __syncthreads();
    if (tid == 0) {
        int acc = 0;
        #pragma unroll
        for (int i = 0; i < 16; ++i) acc += wsum[i];
        blockSums[blockIdx.x] = acc;
    }
}

// ---------------- local scan (fused block-offset scan) -> row_start ----------------
// NOTE: 256 threads exactly (t*4 covers this block's 1024 rows; wsum sized for 4 waves).
__global__ __launch_bounds__(256) void local_scan_kernel(const int* __restrict__ counts,
                                                         const int* __restrict__ blockSums,
                                                         int* __restrict__ row_start) {
    __shared__ int wsum[4];
    __shared__ int boff;
    int t = threadIdx.x;
    // wave 0: scan the 49 block sums; every block computes its own offset
    if (t < 64) {
        int x = (t < SCAN_NBLK) ? blockSums[t] : 0;
        #pragma unroll
        for (int off = 1; off < 64; off <<= 1) {
            int y = __shfl_up(x, off);
            if (t >= off) x += y;
        }
        int excl = __shfl_up(x, 1);
        if (t == 0) excl = 0;
        if (t == blockIdx.x) boff = excl;
        if (blockIdx.x == SCAN_NBLK - 1 && t == SCAN_NBLK - 1)
            row_start[N_NODES] = x;   // grand total
    }
    int base = blockIdx.x * 1024 + t * 4;
    int4 c = make_int4(0, 0, 0, 0);
    if (base < N_NODES) c = *(const int4*)(counts + base);
    int s0 = c.x, s1 = s0 + c.y, s2 = s1 + c.z, s3 = s2 + c.w;
    int tsum = s3;
    int lane = t & 63, wid = t >> 6;
    int x = tsum;
    #pragma unroll
    for (int off = 1; off < 64; off <<= 1) {
        int y = __shfl_up(x, off);
        if (lane >= off) x += y;
    }
    if (lane == 63) wsum[wid] = x;
    __syncthreads();
    int woff = 0;
    for (int i = 0; i < 4; ++i)
        if (i < wid) woff += wsum[i];
    int excl = x - tsum + woff + boff;
    if (base < N_NODES) {
        int4 rs = make_int4(excl, excl + s0, excl + s1, excl + s2);
        *(int4*)(row_start + base) = rs;
    }
}

// ---------------- scatter2: rank via LDS atomic replay (zero global atomics) ----------------
__global__ __launch_bounds__(1024) void scatter2_kernel(const int* __restrict__ rows,
                                                        const int* __restrict__ cols,
                                                        const float* __restrict__ vals,
                                                        const unsigned* __restrict__ base,
                                                        const unsigned* __restrict__ goff,
                                                        const int* __restrict__ row_start,
                                                        unsigned* __restrict__ csr_cv) {
    __shared__ unsigned cur[PK];  // 50 KB: this block's packed per-row bases
    int t = threadIdx.x;
    const uint4* bb = (const uint4*)(base + (size_t)blockIdx.x * PK);
    const uint4* gg = (const uint4*)(goff + (size_t)(blockIdx.x >> 6) * PK);
    for (int i = t; i < PK / 4; i += 1024) {
        uint4 b = bb[i], o = gg[i];
        // byte-parallel add: per-row sums < 256 so no cross-byte carries
        ((uint4*)cur)[i] = make_uint4(b.x + o.x, b.y + o.y, b.z + o.z, b.w + o.w);
    }
    __syncthreads();
    int e0 = blockIdx.x * EPB;
    for (int i = t; i < EPB; i += 1024) {
        int e = e0 + i;
        int r = rows[e];
        unsigned sh = (unsigned)(r & 3) * 8u;
        unsigned old = atomicAdd(&cur[r >> 2], 1u << sh);   // LDS atomic
        int pos = row_start[r] + (int)((old >> sh) & 0xffu);
        csr_cv[pos] = ((unsigned)cols[e] << 16) | bf16bits(vals[e]);
    }
}

// ---------------- SpMM (CSR, quarter-wave per edge, 16-edge unrolled gathers) ----------------
// lane = 16p+q: p = edge-of-quad, q = dim group of 8 (one 16B chunk of the row).
// Inner loop handles 16 edges (4 quads) per iteration: FOUR independent dwordx4
// gathers in flight per lane (MLP=4). Zero-padding beyond cnt (u=0 -> col 0, val +0.0)
// makes over-run exact; pad gathers broadcast row 0 (L1 hit).
// MODE 0: Hout[r] = bf16(acc)                               (hop 2)
// MODE 1: Hout[r] = bf16(0.5*acc)                           (hop 1, folds input scale)
// MODE 2: Hout[r] = bf16(0.5*feats[r] + h1[r] + h2[r] + acc)   (hop 3, y in bf16)
template <int MODE>
__global__ void spmm_csr(const int* __restrict__ row_start,
                         const unsigned* __restrict__ csr_cv,
                         const uintx4* __restrict__ Hin4,
                         uintx4* __restrict__ Hout4,
                         const float* __restrict__ feats,
                         const uintx4* __restrict__ h1b4,
                         const uintx4* __restrict__ h2b4) {
    int wave = (blockIdx.x * blockDim.x + threadIdx.x) >> 6;
    int lane = threadIdx.x & 63;
    if (wave >= N_NODES) return;
    int p = lane >> 4;          // 0..3: which edge of the quad
    int q = lane & 15;          // dim group (8 dims = 16 B)
    int start = row_start[wave];
    int end   = row_start[wave + 1];
    float acc[8] = {};
    for (int base = start; base < end; base += 64) {
        int idx = base + lane;
        unsigned u = 0;                         // col=0, val=+0.0 padding
        if (idx < end) u = __builtin_nontemporal_load(csr_cv + idx);
        int cnt = min(64, end - base);
        for (int j = 0; j < cnt; j += 16) {
            unsigned uj0 = __shfl(u, j + p);
            unsigned uj1 = __shfl(u, j + 4 + p);
            unsigned uj2 = __shfl(u, j + 8 + p);
            unsigned uj3 = __shfl(u, j + 12 + p);   // <= 63: ok
            int c0 = uj0 >> 16, c1 = uj1 >> 16, c2 = uj2 >> 16, c3 = uj3 >> 16;
            float v0 = __uint_as_float(uj0 << 16);
            float v1 = __uint_as_float(uj1 << 16);
            float v2 = __uint_as_float(uj2 << 16);
            float v3 = __uint_as_float(uj3 << 16);
            uintx4 h0 = Hin4[(size_t)c0 * 16 + q];   // 4 independent gathers in flight
            uintx4 h1 = Hin4[(size_t)c1 * 16 + q];
            uintx4 h2 = Hin4[(size_t)c2 * 16 + q];
            uintx4 h3 = Hin4[(size_t)c3 * 16 + q];
            acc[0] += v0 * bf_lo(h0.x); acc[1] += v0 * bf_hi(h0.x);
            acc[2] += v0 * bf_lo(h0.y); acc[3] += v0 * bf_hi(h0.y);
            acc[4] += v0 * bf_lo(h0.z); acc[5] += v0 * bf_hi(h0.z);
            acc[6] += v0 * bf_lo(h0.w); acc[7] += v0 * bf_hi(h0.w);
            acc[0] += v1 * bf_lo(h1.x); acc[1] += v1 * bf_hi(h1.x);
            acc[2] += v1 * bf_lo(h1.y); acc[3] += v1 * bf_hi(h1.y);
            acc[4] += v1 * bf_lo(h1.z); acc[5] += v1 * bf_hi(h1.z);
            acc[6] += v1 * bf_lo(h1.w); acc[7] += v1 * bf_hi(h1.w);
            acc[0] += v2 * bf_lo(h2.x); acc[1] += v2 * bf_hi(h2.x);
            acc[2] += v2 * bf_lo(h2.y); acc[3] += v2 * bf_hi(h2.y);
            acc[4] += v2 * bf_lo(h2.z); acc[5] += v2 * bf_hi(h2.z);
            acc[6] += v2 * bf_lo(h2.w); acc[7] += v2 * bf_hi(h2.w);
            acc[0] += v3 * bf_lo(h3.x); acc[1] += v3 * bf_hi(h3.x);
            acc[2] += v3 * bf_lo(h3.y); acc[3] += v3 * bf_hi(h3.y);
            acc[4] += v3 * bf_lo(h3.z); acc[5] += v3 * bf_hi(h3.z);
            acc[6] += v3 * bf_lo(h3.w); acc[7] += v3 * bf_hi(h3.w);
        }
    }
    // reduce the 4 edge-subsets (lane bits 4..5)
    #pragma unroll
    for (int i = 0; i < 8; ++i) {
        acc[i] += __shfl_xor(acc[i], 16);
        acc[i] += __shfl_xor(acc[i], 32);
    }
    if (p == 0) {
        size_t o16 = (size_t)wave * 16 + q;
        if (MODE == 1) {
            #pragma unroll
            for (int i = 0; i < 8; ++i) acc[i] *= 0.5f;
        } else if (MODE == 2) {
            size_t of = (size_t)wave * IN_DIM + q * 8;
            floatx4 f0 = __builtin_nontemporal_load((const floatx4*)(feats + of));
            floatx4 f1 = __builtin_nontemporal_load((const floatx4*)(feats + of + 4));
            uintx4 a = __builtin_nontemporal_load(h1b4 + o16);
            uintx4 b = __builtin_nontemporal_load(h2b4 + o16);
            acc[0] += 0.5f * f0.x + bf_lo(a.x) + bf_lo(b.x);
            acc[1] += 0.5f * f0.y + bf_hi(a.x) + bf_hi(b.x);
            acc[2] += 0.5f * f0.z + bf_lo(a.y) + bf_lo(b.y);
            acc[3] += 0.5f * f0.w + bf_hi(a.y) + bf_hi(b.y);
            acc[4] += 0.5f * f1.x + bf_lo(a.z) + bf_lo(b.z);
            acc[5] += 0.5f * f1.y + bf_hi(a.z) + bf_hi(b.z);
            acc[6] += 0.5f * f1.z + bf_lo(a.w) + bf_lo(b.w);
            acc[7] += 0.5f * f1.w + bf_hi(a.w) + bf_hi(b.w);
        }
        uintx4 rv;
        rv.x = bf16pair(acc[0], acc[1]);
        rv.y = bf16pair(acc[2], acc[3]);
        rv.z = bf16pair(acc[4], acc[5]);
        rv.w = bf16pair(acc[6], acc[7]);
        __builtin_nontemporal_store(rv, Hout4 + o16);
    }
}

// ---------------- fused MLP: relu(0.25*(ybf@W1)+b1) @ W2 + b2 -> double log_softmax -------
// One block = 64 rows, 4 waves (wave w owns rows w*16..w*16+15 for BOTH gemms).
// gemm1: W1 fragments staged in 16KB quarters; C-frags relu'd, packed bf16 into LDS
// (row stride 132 u32 = 264 ushorts: 16B-aligned A-frag reads, only 2-way bank aliasing).
// gemm2: A-frags read from LDS, B = prepacked W2 bf16 frags (cols padded 40->48).
// Epilogue: +b2, double log_softmax via 16-lane shuffle groups, write 40 cols.
#define H1_STRIDE 264   // ushorts per row (132 u32)
__global__ __launch_bounds__(256) void mlp_fused(const uint4* __restrict__ yb4,
                                                 const uint4* __restrict__ W1frag,
                                                 const uint4* __restrict__ W2frag,
                                                 const float* __restrict__ bias1,
                                                 const float* __restrict__ b2,
                                                 float* __restrict__ Out) {
    __shared__ uint4 shA[1536];                       // 24 KB: W1 quarter / W2 frags
    __shared__ unsigned short h1u[64 * H1_STRIDE];    // 33 KB: H1 tile, bf16
    int tid = threadIdx.x;
    int w = tid >> 6, lane = tid & 63;
    int q = lane >> 4, c16 = lane & 15;
    int row0 = blockIdx.x * 64;
    int arow = row0 + w * 16 + c16;

    union { uint4 u; short8 v; } au[4], bu, af;
    if (arow < N_NODES) {
        #pragma unroll
        for (int s = 0; s < 4; ++s)
            au[s].u = yb4[(size_t)arow * 16 + 4 * s + q];
    } else {
        #pragma unroll
        for (int s = 0; s < 4; ++s)
            au[s].u = make_uint4(0u, 0u, 0u, 0u);
    }

    // ---- gemm1 in 4 quarter-stages (h, tq) ----
    for (int h = 0; h < 2; ++h) {
        for (int tq = 0; tq < 2; ++tq) {
            __syncthreads();   // protect shA from readers of previous stage
            #pragma unroll
            for (int i = tid; i < 1024; i += 256)
                shA[i] = W1frag[h * 2048 + tq * 1024 + i];
            __syncthreads();
            #pragma unroll
            for (int t2 = 0; t2 < 4; ++t2) {
                floatx4 acc = {0.f, 0.f, 0.f, 0.f};
                #pragma unroll
                for (int s = 0; s < 4; ++s) {
                    bu.u = shA[(t2 * 4 + s) * 64 + lane];
                    acc = __builtin_amdgcn_mfma_f32_16x16x32_bf16(au[s].v, bu.v, acc, 0, 0, 0);
                }
                int col = h * 128 + (tq * 4 + t2) * 16 + c16;
                float bs = bias1[col];
                #pragma unroll
                for (int r = 0; r < 4; ++r) {
                    float v = 0.25f * acc[r] + bs;
                    v = v > 0.f ? v : 0.f;
                    h1u[(w * 16 + q * 4 + r) * H1_STRIDE + col] =
                        (unsigned short)bf16bits(v);
                }
            }
        }
    }
    __syncthreads();
    // ---- stage W2 fragments ----
    #pragma unroll
    for (int i = tid; i < 1536; i += 256)
        shA[i] = W2frag[i];
    __syncthreads();

    // ---- gemm2: wave w owns row-tile w ----
    floatx4 acc2[3] = {{0.f,0.f,0.f,0.f},{0.f,0.f,0.f,0.f},{0.f,0.f,0.f,0.f}};
    const unsigned* h1w = (const unsigned*)h1u;
    #pragma unroll
    for (int ks = 0; ks < 8; ++ks) {
        af.u = *(const uint4*)&h1w[(w * 16 + c16) * (H1_STRIDE / 2) + ks * 16 + q * 4];
        #pragma unroll
        for (int nt = 0; nt < 3; ++nt) {
            bu.u = shA[nt * 512 + ks * 64 + lane];
            acc2[nt] = __builtin_amdgcn_mfma_f32_16x16x32_bf16(af.v, bu.v, acc2[nt], 0, 0, 0);
        }
    }

    // ---- +b2, double log_softmax (rows span 16-lane groups), write ----
    float bb[3];
    #pragma unroll
    for (int nt = 0; nt < 3; ++nt) {
        int col = nt * 16 + c16;
        bb[nt] = (col < NCLASS) ? b2[col] : 0.f;
    }
    #pragma unroll
    for (int r = 0; r < 4; ++r) {
        int gr = row0 + w * 16 + q * 4 + r;
        float z[3];
        #pragma unroll
        for (int nt = 0; nt < 3; ++nt) z[nt] = acc2[nt][r] + bb[nt];
        if (c16 >= 8) z[2] = -INFINITY;   // cols 40..47 are padding
        float m = fmaxf(fmaxf(z[0], z[1]), z[2]);
        #pragma unroll
        for (int off = 1; off < 16; off <<= 1) m = fmaxf(m, __shfl_xor(m, off));
        float s = expf(z[0] - m) + expf(z[1] - m) + ((c16 < 8) ? expf(z[2] - m) : 0.f);
        #pragma unroll
        for (int off = 1; off < 16; off <<= 1) s += __shfl_xor(s, off);
        float l1 = m + logf(s);
        #pragma unroll
        for (int nt = 0; nt < 3; ++nt) z[nt] -= l1;
        float m2 = fmaxf(fmaxf(z[0], z[1]), z[2]);
        #pragma unroll
        for (int off = 1; off < 16; off <<= 1) m2 = fmaxf(m2, __shfl_xor(m2, off));
        float s2 = expf(z[0] - m2) + expf(z[1] - m2) + ((c16 < 8) ? expf(z[2] - m2) : 0.f);
        #pragma unroll
        for (int off = 1; off < 16; off <<= 1) s2 += __shfl_xor(s2, off);
        float l2 = m2 + logf(s2);
        if (gr < N_NODES) {
            #pragma unroll
            for (int nt = 0; nt < 3; ++nt) {
                int col = nt * 16 + c16;
                if (col < NCLASS)
                    Out[(size_t)gr * NCLASS + col] = z[nt] - l2;
            }
        }
    }
}

extern "C" void kernel_launch(void* const* d_in, const int* in_sizes, int n_in,
                              void* d_out, int out_size, void* d_ws, size_t ws_size,
                              hipStream_t stream) {
    const float* feats   = (const float*)d_in[0];
    const int*   e_row   = (const int*)d_in[1];
    const int*   e_col   = (const int*)d_in[2];
    const float* e_vals  = (const float*)d_in[3];
    const float* W1      = (const float*)d_in[4];
    const float* b1      = (const float*)d_in[5];
    const float* W2      = (const float*)d_in[6];
    const float* b2      = (const float*)d_in[7];
    float* out = (float*)d_out;

    // Workspace (19.2M floats proven):
    //   hist  : [0, 3.2M)           256 x 12500 packed u32 (12.8 MB; dead after colscan)
    //   ybf   : [0, 3.2M)           y in bf16 (MLP input, written by hop3)
    //   W1frag: [3.2M, 3.217M)      W1 bf16 MFMA fragments (64 KB)
    //   W2frag: [3.25M, 3.257M)     W2 bf16 MFMA fragments (24 KB)
    //   counts: [3.3M, 3.35M)       per-row degrees (dead after local_scan)
    //   goff  : [3.4M, 3.45M)       colscan group offsets (dead after scatter)
    //   fb16  : [6.4M, 9.6M)        feats in bf16
    //   h1b   : [9.6M, 12.8M)       hop1 out, bf16
    //   h2b   : [12.8M, 16M)        hop2 out, bf16
    //   base  : [16M, 19.2M)        per-(block,row) packed bases (dead after scatter)
    float* ws    = (float*)d_ws;
    uint4* ybf4  = (uint4*)ws;
    unsigned* hist = (unsigned*)ws;
    uint4* W1frag = (uint4*)(ws + (size_t)N_NODES * IN_DIM / 2);
    uint4* W2frag = (uint4*)(ws + 3250000);
    int*   counts = (int*)(ws + 3300000);
    unsigned* goff = (unsigned*)(ws + 3400000);
    uint4* fb16_4 = (uint4*)(ws + (size_t)N_NODES * IN_DIM);
    uint4* h1b4  = (uint4*)(ws + (size_t)N_NODES * IN_DIM * 3 / 2);
    uint4* h2b4  = (uint4*)(ws + (size_t)N_NODES * IN_DIM * 2);
    unsigned* basep = (unsigned*)(ws + (size_t)N_NODES * IN_DIM * 5 / 2);   // 16M..19.2M

    // CSR scratch in d_out (8 MB; fully overwritten by mlp_fused at the end).
    unsigned* csr_cv = (unsigned*)d_out;                 // packed (col<<16)|bf16(val), 800000
    int*   row_start = (int*)d_out + 2 * N_EDGES;        // [1600000, 1650001)
    int*   blockSums = row_start + N_NODES + 4;          // < 2000000

    // prep: feats->bf16 + W1/W2 fragment pack (pure streaming, no atomics)
    const int ELEMS4 = N_NODES * IN_DIM / 4;  // 1.6M float4s
    prep_kernel<<<ELEMS4 / 256, 256, 0, stream>>>((const float4*)feats, (uint2*)fb16_4,
                                                  W1, W1frag, W2, W2frag);

    // CSR build, zero global atomics:
    // privatized LDS histograms -> 4-way parallel column scan -> fused hierarchical row scan
    // -> LDS-replay scatter (byte-parallel base+goff)
    hist_kernel<<<HBLK, 1024, 0, stream>>>(e_row, hist);
    colscan_kernel<<<SCAN_NBLK, 1024, 0, stream>>>(hist, basep, goff, counts, blockSums);
    local_scan_kernel<<<SCAN_NBLK, 256, 0, stream>>>(counts, blockSums, row_start);
    scatter2_kernel<<<HBLK, 1024, 0, stream>>>(e_row, e_col, e_vals, basep, goff,
                                               row_start, csr_cv);

    // 3 propagation hops (quarter-wave per edge, 16-edge unrolled: 4 gathers in flight)
    const int SPMM_BLOCKS = N_NODES / 4;      // 12500 (4 waves/block)
    spmm_csr<1><<<SPMM_BLOCKS, 256, 0, stream>>>(row_start, csr_cv, (const uintx4*)fb16_4,
                                                 (uintx4*)h1b4, nullptr, nullptr, nullptr);
    spmm_csr<0><<<SPMM_BLOCKS, 256, 0, stream>>>(row_start, csr_cv, (const uintx4*)h1b4,
                                                 (uintx4*)h2b4, nullptr, nullptr, nullptr);
    spmm_csr<2><<<SPMM_BLOCKS, 256, 0, stream>>>(row_start, csr_cv, (const uintx4*)h2b4,
                                                 (uintx4*)ybf4, feats,
                                                 (const uintx4*)h1b4, (const uintx4*)h2b4);

    // fused MLP: relu(0.25*(ybf@W1)+b1) @ W2 + b2 -> double log_softmax -> out
    mlp_fused<<<(N_NODES + 63) / 64, 256, 0, stream>>>(ybf4, W1frag, W2frag, b1, b2, out);
}

// Round 6
// 229.119 us; speedup vs baseline: 1.8216x; 1.0238x over previous
//
#include <hip/hip_runtime.h>
#include <math.h>

#define N_NODES 50000
#define N_EDGES 800000
#define IN_DIM 128
#define HID 256
#define NCLASS 40

#define SCAN_NBLK 49   // ceil(50000 / 1024)

// CSR build: 256 privatized histogram blocks, 8-bit packed counters (4 rows/u32)
#define HBLK 256
#define EPB  3125      // edges per hist block: 256 * 3125 = 800000 exactly
#define PK   12500     // packed u32 bins (50000 rows / 4)
#define CS_G 4         // colscan hist groups
#define CS_HPG 64      // hists per group (256/4)

typedef __attribute__((ext_vector_type(8))) short short8;
typedef __attribute__((ext_vector_type(4))) float floatx4;
typedef __attribute__((ext_vector_type(4))) unsigned uintx4;

// ---------- bf16 helpers (RNE pack, cheap unpack) ----------
__device__ inline unsigned bf16pair(float a, float b) {
    unsigned ua = __float_as_uint(a), ub = __float_as_uint(b);
    ua = (ua + 0x7fffu + ((ua >> 16) & 1u)) >> 16;
    ub = (ub + 0x7fffu + ((ub >> 16) & 1u)) >> 16;
    return ua | (ub << 16);
}
__device__ inline unsigned bf16bits(float a) {
    unsigned ua = __float_as_uint(a);
    return (ua + 0x7fffu + ((ua >> 16) & 1u)) >> 16;
}
__device__ inline float bf_lo(unsigned u) { return __uint_as_float(u << 16); }
__device__ inline float bf_hi(unsigned u) { return __uint_as_float(u & 0xffff0000u); }

// ---------------- prep: feats->bf16 + W1/W2 fragment pack (atomic-free streaming) -------------
__global__ void prep_kernel(const float4* __restrict__ f4,
                            uint2* __restrict__ fb16,
                            const float* __restrict__ W1,
                            uint4* __restrict__ W1frag,
                            const float* __restrict__ W2,
                            uint4* __restrict__ W2frag) {
    int i = blockIdx.x * blockDim.x + threadIdx.x;   // < 1.6M
    float4 v = f4[i];
    fb16[i] = make_uint2(bf16pair(v.x, v.y), bf16pair(v.z, v.w));
    if (i < 4096) {
        int f = i;
        int h = f >> 11, rem = f & 2047;
        int t = rem >> 8, s = (rem >> 6) & 3, l = rem & 63;
        int q = l >> 4, n16 = l & 15;
        int n = h * 128 + t * 16 + n16;
        int kb = s * 32 + q * 8;
        unsigned p[4];
        #pragma unroll
        for (int jj = 0; jj < 4; ++jj) {
            float a = W1[(size_t)(kb + 2 * jj) * HID + n];
            float b = W1[(size_t)(kb + 2 * jj + 1) * HID + n];
            p[jj] = bf16pair(a, b);
        }
        W1frag[f] = make_uint4(p[0], p[1], p[2], p[3]);
    } else if (i < 4096 + 1536) {
        // W2 B-fragments: [nt(3)][ks(8)][lane(64)], cols padded 40->48 with zeros
        int f2 = i - 4096;
        int nt = f2 >> 9;           // /512
        int rem = f2 & 511;
        int ks = rem >> 6, l = rem & 63;
        int col = nt * 16 + (l & 15);
        int k = ks * 32 + (l >> 4) * 8;
        unsigned p[4];
        #pragma unroll
        for (int jj = 0; jj < 4; ++jj) {
            float a = (col < NCLASS) ? W2[(size_t)(k + 2 * jj) * NCLASS + col] : 0.f;
            float b = (col < NCLASS) ? W2[(size_t)(k + 2 * jj + 1) * NCLASS + col] : 0.f;
            p[jj] = bf16pair(a, b);
        }
        W2frag[f2] = make_uint4(p[0], p[1], p[2], p[3]);
    }
}

// ---------------- hist: per-block privatized LDS histogram, 8-bit packed ----------------
__global__ __launch_bounds__(1024) void hist_kernel(const int* __restrict__ rows,
                                                    unsigned* __restrict__ hist) {
    __shared__ unsigned h[PK];    // 50 KB
    int t = threadIdx.x;
    for (int i = t; i < PK / 4; i += 1024)
        ((uint4*)h)[i] = make_uint4(0u, 0u, 0u, 0u);
    __syncthreads();
    int e0 = blockIdx.x * EPB;
    for (int i = t; i < EPB; i += 1024) {
        int r = rows[e0 + i];
        atomicAdd(&h[r >> 2], 1u << ((r & 3) * 8));   // LDS atomic
    }
    __syncthreads();
    unsigned* out = hist + (size_t)blockIdx.x * PK;
    for (int i = t; i < PK / 4; i += 1024)
        ((uint4*)out)[i] = ((const uint4*)h)[i];
}

// ---------------- colscan v2: 4-way parallel per-row prefix across 256 block-histograms ----
__global__ __launch_bounds__(1024) void colscan_kernel(const unsigned* __restrict__ hist,
                                                       unsigned* __restrict__ base,
                                                       unsigned* __restrict__ goff,
                                                       int* __restrict__ counts,
                                                       int* __restrict__ blockSums) {
    __shared__ unsigned lsum[CS_G][256];
    int tid = threadIdx.x;          // 1024
    int g = tid >> 8;               // 0..3 hist group
    int c = tid & 255;              // col-quad within block
    int colq = blockIdx.x * 256 + c;
    unsigned run = 0;               // 4 packed 8-bit running sums (degree < 256: no overflow)
    if (colq < PK) {
        #pragma unroll 8
        for (int i = 0; i < CS_HPG; ++i) {
            int b = g * CS_HPG + i;
            unsigned v = hist[(size_t)b * PK + colq];
            base[(size_t)b * PK + colq] = run;
            run += v;
        }
    }
    lsum[g][c] = run;
    __syncthreads();
    unsigned off = 0;
    #pragma unroll
    for (int gg = 0; gg < CS_G; ++gg) {
        unsigned v = lsum[gg][c];
        if (gg < g) off += v;
    }
    unsigned tot = off + run;       // valid for g == CS_G-1: full per-row degrees (packed)
    if (colq < PK) {
        goff[(size_t)g * PK + colq] = off;
        if (g == CS_G - 1)
            *(int4*)(counts + 4 * colq) = make_int4((int)(tot & 0xffu), (int)((tot >> 8) & 0xffu),
                                                    (int)((tot >> 16) & 0xffu), (int)(tot >> 24));
    }
    // per-scanblock edge-count sum (rows [blk*1024, blk*1024+1024))
    int s = 0;
    if (g == CS_G - 1 && colq < PK)
        s = (int)((tot & 0xffu) + ((tot >> 8) & 0xffu) + ((tot >> 16) & 0xffu) + (tot >> 24));
    #pragma unroll
    for (int o = 32; o >= 1; o >>= 1)
        s += __shfl_xor(s, o);
    __shared__ int wsum[16];
    int lane = tid & 63, wid = tid >> 6;
    if (lane == 0) wsum[wid] = s;
    __syncthreads();
    if (tid == 0) {
        int acc = 0;
        #pragma unroll
        for (int i = 0; i < 16; ++i) acc += wsum[i];
        blockSums[blockIdx.x] = acc;
    }
}

// ---------------- local scan (fused block-offset scan) -> row_start ----------------
// NOTE: 256 threads exactly (t*4 covers this block's 1024 rows; wsum sized for 4 waves).
__global__ __launch_bounds__(256) void local_scan_kernel(const int* __restrict__ counts,
                                                         const int* __restrict__ blockSums,
                                                         int* __restrict__ row_start) {
    __shared__ int wsum[4];
    __shared__ int boff;
    int t = threadIdx.x;
    // wave 0: scan the 49 block sums; every block computes its own offset
    if (t < 64) {
        int x = (t < SCAN_NBLK) ? blockSums[t] : 0;
        #pragma unroll
        for (int off = 1; off < 64; off <<= 1) {
            int y = __shfl_up(x, off);
            if (t >= off) x += y;
        }
        int excl = __shfl_up(x, 1);
        if (t == 0) excl = 0;
        if (t == blockIdx.x) boff = excl;
        if (blockIdx.x == SCAN_NBLK - 1 && t == SCAN_NBLK - 1)
            row_start[N_NODES] = x;   // grand total
    }
    int base = blockIdx.x * 1024 + t * 4;
    int4 c = make_int4(0, 0, 0, 0);
    if (base < N_NODES) c = *(const int4*)(counts + base);
    int s0 = c.x, s1 = s0 + c.y, s2 = s1 + c.z, s3 = s2 + c.w;
    int tsum = s3;
    int lane = t & 63, wid = t >> 6;
    int x = tsum;
    #pragma unroll
    for (int off = 1; off < 64; off <<= 1) {
        int y = __shfl_up(x, off);
        if (lane >= off) x += y;
    }
    if (lane == 63) wsum[wid] = x;
    __syncthreads();
    int woff = 0;
    for (int i = 0; i < 4; ++i)
        if (i < wid) woff += wsum[i];
    int excl = x - tsum + woff + boff;
    if (base < N_NODES) {
        int4 rs = make_int4(excl, excl + s0, excl + s1, excl + s2);
        *(int4*)(row_start + base) = rs;
    }
}

// ---------------- scatter2: rank via LDS atomic replay (zero global atomics) ----------------
__global__ __launch_bounds__(1024) void scatter2_kernel(const int* __restrict__ rows,
                                                        const int* __restrict__ cols,
                                                        const float* __restrict__ vals,
                                                        const unsigned* __restrict__ base,
                                                        const unsigned* __restrict__ goff,
                                                        const int* __restrict__ row_start,
                                                        unsigned* __restrict__ csr_cv) {
    __shared__ unsigned cur[PK];  // 50 KB: this block's packed per-row bases
    int t = threadIdx.x;
    const uint4* bb = (const uint4*)(base + (size_t)blockIdx.x * PK);
    const uint4* gg = (const uint4*)(goff + (size_t)(blockIdx.x >> 6) * PK);
    for (int i = t; i < PK / 4; i += 1024) {
        uint4 b = bb[i], o = gg[i];
        // byte-parallel add: per-row sums < 256 so no cross-byte carries
        ((uint4*)cur)[i] = make_uint4(b.x + o.x, b.y + o.y, b.z + o.z, b.w + o.w);
    }
    __syncthreads();
    int e0 = blockIdx.x * EPB;
    for (int i = t; i < EPB; i += 1024) {
        int e = e0 + i;
        int r = rows[e];
        unsigned sh = (unsigned)(r & 3) * 8u;
        unsigned old = atomicAdd(&cur[r >> 2], 1u << sh);   // LDS atomic
        int pos = row_start[r] + (int)((old >> sh) & 0xffu);
        csr_cv[pos] = ((unsigned)cols[e] << 16) | bf16bits(vals[e]);
    }
}

// ---------------- SpMM (CSR, quarter-wave per edge, 16-edge unrolled gathers) ----------------
// lane = 16p+q: p = edge-of-quad, q = dim group of 8 (one 16B chunk of the row).
// Inner loop handles 16 edges (4 quads) per iteration: FOUR independent dwordx4
// gathers in flight per lane (MLP=4). Zero-padding beyond cnt (u=0 -> col 0, val +0.0)
// makes over-run exact; pad gathers broadcast row 0 (L1 hit).
// MODE 0: Hout[r] = bf16(acc)                               (hop 2)
// MODE 1: Hout[r] = bf16(0.5*acc)                           (hop 1, folds input scale)
// MODE 2: Hout[r] = bf16(0.5*feats[r] + h1[r] + h2[r] + acc)   (hop 3, y in bf16)
template <int MODE>
__global__ void spmm_csr(const int* __restrict__ row_start,
                         const unsigned* __restrict__ csr_cv,
                         const uintx4* __restrict__ Hin4,
                         uintx4* __restrict__ Hout4,
                         const float* __restrict__ feats,
                         const uintx4* __restrict__ h1b4,
                         const uintx4* __restrict__ h2b4) {
    int wave = (blockIdx.x * blockDim.x + threadIdx.x) >> 6;
    int lane = threadIdx.x & 63;
    if (wave >= N_NODES) return;
    int p = lane >> 4;          // 0..3: which edge of the quad
    int q = lane & 15;          // dim group (8 dims = 16 B)
    int start = row_start[wave];
    int end   = row_start[wave + 1];
    float acc[8] = {};
    for (int base = start; base < end; base += 64) {
        int idx = base + lane;
        unsigned u = 0;                         // col=0, val=+0.0 padding
        if (idx < end) u = __builtin_nontemporal_load(csr_cv + idx);
        int cnt = min(64, end - base);
        for (int j = 0; j < cnt; j += 16) {
            unsigned uj0 = __shfl(u, j + p);
            unsigned uj1 = __shfl(u, j + 4 + p);
            unsigned uj2 = __shfl(u, j + 8 + p);
            unsigned uj3 = __shfl(u, j + 12 + p);   // <= 63: ok
            int c0 = uj0 >> 16, c1 = uj1 >> 16, c2 = uj2 >> 16, c3 = uj3 >> 16;
            float v0 = __uint_as_float(uj0 << 16);
            float v1 = __uint_as_float(uj1 << 16);
            float v2 = __uint_as_float(uj2 << 16);
            float v3 = __uint_as_float(uj3 << 16);
            uintx4 h0 = Hin4[(size_t)c0 * 16 + q];   // 4 independent gathers in flight
            uintx4 h1 = Hin4[(size_t)c1 * 16 + q];
            uintx4 h2 = Hin4[(size_t)c2 * 16 + q];
            uintx4 h3 = Hin4[(size_t)c3 * 16 + q];
            acc[0] += v0 * bf_lo(h0.x); acc[1] += v0 * bf_hi(h0.x);
            acc[2] += v0 * bf_lo(h0.y); acc[3] += v0 * bf_hi(h0.y);
            acc[4] += v0 * bf_lo(h0.z); acc[5] += v0 * bf_hi(h0.z);
            acc[6] += v0 * bf_lo(h0.w); acc[7] += v0 * bf_hi(h0.w);
            acc[0] += v1 * bf_lo(h1.x); acc[1] += v1 * bf_hi(h1.x);
            acc[2] += v1 * bf_lo(h1.y); acc[3] += v1 * bf_hi(h1.y);
            acc[4] += v1 * bf_lo(h1.z); acc[5] += v1 * bf_hi(h1.z);
            acc[6] += v1 * bf_lo(h1.w); acc[7] += v1 * bf_hi(h1.w);
            acc[0] += v2 * bf_lo(h2.x); acc[1] += v2 * bf_hi(h2.x);
            acc[2] += v2 * bf_lo(h2.y); acc[3] += v2 * bf_hi(h2.y);
            acc[4] += v2 * bf_lo(h2.z); acc[5] += v2 * bf_hi(h2.z);
            acc[6] += v2 * bf_lo(h2.w); acc[7] += v2 * bf_hi(h2.w);
            acc[0] += v3 * bf_lo(h3.x); acc[1] += v3 * bf_hi(h3.x);
            acc[2] += v3 * bf_lo(h3.y); acc[3] += v3 * bf_hi(h3.y);
            acc[4] += v3 * bf_lo(h3.z); acc[5] += v3 * bf_hi(h3.z);
            acc[6] += v3 * bf_lo(h3.w); acc[7] += v3 * bf_hi(h3.w);
        }
    }
    // reduce the 4 edge-subsets (lane bits 4..5)
    #pragma unroll
    for (int i = 0; i < 8; ++i) {
        acc[i] += __shfl_xor(acc[i], 16);
        acc[i] += __shfl_xor(acc[i], 32);
    }
    if (p == 0) {
        size_t o16 = (size_t)wave * 16 + q;
        if (MODE == 1) {
            #pragma unroll
            for (int i = 0; i < 8; ++i) acc[i] *= 0.5f;
        } else if (MODE == 2) {
            size_t of = (size_t)wave * IN_DIM + q * 8;
            floatx4 f0 = __builtin_nontemporal_load((const floatx4*)(feats + of));
            floatx4 f1 = __builtin_nontemporal_load((const floatx4*)(feats + of + 4));
            uintx4 a = __builtin_nontemporal_load(h1b4 + o16);
            uintx4 b = __builtin_nontemporal_load(h2b4 + o16);
            acc[0] += 0.5f * f0.x + bf_lo(a.x) + bf_lo(b.x);
            acc[1] += 0.5f * f0.y + bf_hi(a.x) + bf_hi(b.x);
            acc[2] += 0.5f * f0.z + bf_lo(a.y) + bf_lo(b.y);
            acc[3] += 0.5f * f0.w + bf_hi(a.y) + bf_hi(b.y);
            acc[4] += 0.5f * f1.x + bf_lo(a.z) + bf_lo(b.z);
            acc[5] += 0.5f * f1.y + bf_hi(a.z) + bf_hi(b.z);
            acc[6] += 0.5f * f1.z + bf_lo(a.w) + bf_lo(b.w);
            acc[7] += 0.5f * f1.w + bf_hi(a.w) + bf_hi(b.w);
        }
        uintx4 rv;
        rv.x = bf16pair(acc[0], acc[1]);
        rv.y = bf16pair(acc[2], acc[3]);
        rv.z = bf16pair(acc[4], acc[5]);
        rv.w = bf16pair(acc[6], acc[7]);
        __builtin_nontemporal_store(rv, Hout4 + o16);
    }
}

// ---------------- fused MLP v2: B-frags direct from L2, LDS only for H1 transpose ----------
// One block = 64 rows, 4 waves; wave w owns rows w*16..w*16+15 for BOTH gemms.
// W1frag (64 KB) and W2frag (24 KB) are read by every block -> L2-resident; reading them
// per-MFMA from global (16 B/lane) replaces the old 5x barrier-staged LDS rounds.
// LDS holds only the 33 KB H1 bf16 tile (within-wave C->A transpose); 1 barrier total.
#define H1_STRIDE 264   // ushorts per row (132 u32)
__global__ __launch_bounds__(256) void mlp_fused(const uint4* __restrict__ yb4,
                                                 const uint4* __restrict__ W1frag,
                                                 const uint4* __restrict__ W2frag,
                                                 const float* __restrict__ bias1,
                                                 const float* __restrict__ b2,
                                                 float* __restrict__ Out) {
    __shared__ unsigned short h1u[64 * H1_STRIDE];    // 33 KB: H1 tile, bf16
    int tid = threadIdx.x;
    int w = tid >> 6, lane = tid & 63;
    int q = lane >> 4, c16 = lane & 15;
    int row0 = blockIdx.x * 64;
    int arow = row0 + w * 16 + c16;

    union { uint4 u; short8 v; } au[4], bu, af;
    if (arow < N_NODES) {
        #pragma unroll
        for (int s = 0; s < 4; ++s)
            au[s].u = yb4[(size_t)arow * 16 + 4 * s + q];
    } else {
        #pragma unroll
        for (int s = 0; s < 4; ++s)
            au[s].u = make_uint4(0u, 0u, 0u, 0u);
    }

    // ---- gemm1: 16 col-tiles, B-frags straight from L2 ----
    #pragma unroll 4
    for (int ct = 0; ct < 16; ++ct) {
        floatx4 acc = {0.f, 0.f, 0.f, 0.f};
        #pragma unroll
        for (int s = 0; s < 4; ++s) {
            bu.u = W1frag[(ct * 4 + s) * 64 + lane];
            acc = __builtin_amdgcn_mfma_f32_16x16x32_bf16(au[s].v, bu.v, acc, 0, 0, 0);
        }
        int col = ct * 16 + c16;
        float bs = bias1[col];
        #pragma unroll
        for (int r = 0; r < 4; ++r) {
            float v = 0.25f * acc[r] + bs;
            v = v > 0.f ? v : 0.f;
            h1u[(w * 16 + q * 4 + r) * H1_STRIDE + col] = (unsigned short)bf16bits(v);
        }
    }
    __syncthreads();   // within-wave WAR fence on h1u (cheap; only 1 barrier in kernel)

    // ---- gemm2: wave w owns row-tile w; B-frags straight from L2 ----
    floatx4 acc2[3] = {{0.f,0.f,0.f,0.f},{0.f,0.f,0.f,0.f},{0.f,0.f,0.f,0.f}};
    const unsigned* h1w = (const unsigned*)h1u;
    #pragma unroll
    for (int ks = 0; ks < 8; ++ks) {
        af.u = *(const uint4*)&h1w[(w * 16 + c16) * (H1_STRIDE / 2) + ks * 16 + q * 4];
        #pragma unroll
        for (int nt = 0; nt < 3; ++nt) {
            bu.u = W2frag[nt * 512 + ks * 64 + lane];
            acc2[nt] = __builtin_amdgcn_mfma_f32_16x16x32_bf16(af.v, bu.v, acc2[nt], 0, 0, 0);
        }
    }

    // ---- +b2, double log_softmax (rows span 16-lane groups), write ----
    float bb[3];
    #pragma unroll
    for (int nt = 0; nt < 3; ++nt) {
        int col = nt * 16 + c16;
        bb[nt] = (col < NCLASS) ? b2[col] : 0.f;
    }
    #pragma unroll
    for (int r = 0; r < 4; ++r) {
        int gr = row0 + w * 16 + q * 4 + r;
        float z[3];
        #pragma unroll
        for (int nt = 0; nt < 3; ++nt) z[nt] = acc2[nt][r] + bb[nt];
        if (c16 >= 8) z[2] = -INFINITY;   // cols 40..47 are padding
        float m = fmaxf(fmaxf(z[0], z[1]), z[2]);
        #pragma unroll
        for (int off = 1; off < 16; off <<= 1) m = fmaxf(m, __shfl_xor(m, off));
        float s = expf(z[0] - m) + expf(z[1] - m) + ((c16 < 8) ? expf(z[2] - m) : 0.f);
        #pragma unroll
        for (int off = 1; off < 16; off <<= 1) s += __shfl_xor(s, off);
        float l1 = m + logf(s);
        #pragma unroll
        for (int nt = 0; nt < 3; ++nt) z[nt] -= l1;
        float m2 = fmaxf(fmaxf(z[0], z[1]), z[2]);
        #pragma unroll
        for (int off = 1; off < 16; off <<= 1) m2 = fmaxf(m2, __shfl_xor(m2, off));
        float s2 = expf(z[0] - m2) + expf(z[1] - m2) + ((c16 < 8) ? expf(z[2] - m2) : 0.f);
        #pragma unroll
        for (int off = 1; off < 16; off <<= 1) s2 += __shfl_xor(s2, off);
        float l2 = m2 + logf(s2);
        if (gr < N_NODES) {
            #pragma unroll
            for (int nt = 0; nt < 3; ++nt) {
                int col = nt * 16 + c16;
                if (col < NCLASS)
                    Out[(size_t)gr * NCLASS + col] = z[nt] - l2;
            }
        }
    }
}

extern "C" void kernel_launch(void* const* d_in, const int* in_sizes, int n_in,
                              void* d_out, int out_size, void* d_ws, size_t ws_size,
                              hipStream_t stream) {
    const float* feats   = (const float*)d_in[0];
    const int*   e_row   = (const int*)d_in[1];
    const int*   e_col   = (const int*)d_in[2];
    const float* e_vals  = (const float*)d_in[3];
    const float* W1      = (const float*)d_in[4];
    const float* b1      = (const float*)d_in[5];
    const float* W2      = (const float*)d_in[6];
    const float* b2      = (const float*)d_in[7];
    float* out = (float*)d_out;

    // Workspace (19.2M floats proven):
    //   hist  : [0, 3.2M)           256 x 12500 packed u32 (12.8 MB; dead after colscan)
    //   ybf   : [0, 3.2M)           y in bf16 (MLP input, written by hop3)
    //   W1frag: [3.2M, 3.217M)      W1 bf16 MFMA fragments (64 KB)
    //   W2frag: [3.25M, 3.257M)     W2 bf16 MFMA fragments (24 KB)
    //   counts: [3.3M, 3.35M)       per-row degrees (dead after local_scan)
    //   goff  : [3.4M, 3.45M)       colscan group offsets (dead after scatter)
    //   fb16  : [6.4M, 9.6M)        feats in bf16
    //   h1b   : [9.6M, 12.8M)       hop1 out, bf16
    //   h2b   : [12.8M, 16M)        hop2 out, bf16
    //   base  : [16M, 19.2M)        per-(block,row) packed bases (dead after scatter)
    float* ws    = (float*)d_ws;
    uint4* ybf4  = (uint4*)ws;
    unsigned* hist = (unsigned*)ws;
    uint4* W1frag = (uint4*)(ws + (size_t)N_NODES * IN_DIM / 2);
    uint4* W2frag = (uint4*)(ws + 3250000);
    int*   counts = (int*)(ws + 3300000);
    unsigned* goff = (unsigned*)(ws + 3400000);
    uint4* fb16_4 = (uint4*)(ws + (size_t)N_NODES * IN_DIM);
    uint4* h1b4  = (uint4*)(ws + (size_t)N_NODES * IN_DIM * 3 / 2);
    uint4* h2b4  = (uint4*)(ws + (size_t)N_NODES * IN_DIM * 2);
    unsigned* basep = (unsigned*)(ws + (size_t)N_NODES * IN_DIM * 5 / 2);   // 16M..19.2M

    // CSR scratch in d_out (8 MB; fully overwritten by mlp_fused at the end).
    unsigned* csr_cv = (unsigned*)d_out;                 // packed (col<<16)|bf16(val), 800000
    int*   row_start = (int*)d_out + 2 * N_EDGES;        // [1600000, 1650001)
    int*   blockSums = row_start + N_NODES + 4;          // < 2000000

    // prep: feats->bf16 + W1/W2 fragment pack (pure streaming, no atomics)
    const int ELEMS4 = N_NODES * IN_DIM / 4;  // 1.6M float4s
    prep_kernel<<<ELEMS4 / 256, 256, 0, stream>>>((const float4*)feats, (uint2*)fb16_4,
                                                  W1, W1frag, W2, W2frag);

    // CSR build, zero global atomics:
    // privatized LDS histograms -> 4-way parallel column scan -> fused hierarchical row scan
    // -> LDS-replay scatter (byte-parallel base+goff)
    hist_kernel<<<HBLK, 1024, 0, stream>>>(e_row, hist);
    colscan_kernel<<<SCAN_NBLK, 1024, 0, stream>>>(hist, basep, goff, counts, blockSums);
    local_scan_kernel<<<SCAN_NBLK, 256, 0, stream>>>(counts, blockSums, row_start);
    scatter2_kernel<<<HBLK, 1024, 0, stream>>>(e_row, e_col, e_vals, basep, goff,
                                               row_start, csr_cv);

    // 3 propagation hops (quarter-wave per edge, 16-edge unrolled: 4 gathers in flight)
    const int SPMM_BLOCKS = N_NODES / 4;      // 12500 (4 waves/block)
    spmm_csr<1><<<SPMM_BLOCKS, 256, 0, stream>>>(row_start, csr_cv, (const uintx4*)fb16_4,
                                                 (uintx4*)h1b4, nullptr, nullptr, nullptr);
    spmm_csr<0><<<SPMM_BLOCKS, 256, 0, stream>>>(row_start, csr_cv, (const uintx4*)h1b4,
                                                 (uintx4*)h2b4, nullptr, nullptr, nullptr);
    spmm_csr<2><<<SPMM_BLOCKS, 256, 0, stream>>>(row_start, csr_cv, (const uintx4*)h2b4,
                                                 (uintx4*)ybf4, feats,
                                                 (const uintx4*)h1b4, (const uintx4*)h2b4);

    // fused MLP v2: relu(0.25*(ybf@W1)+b1) @ W2 + b2 -> double log_softmax -> out
    mlp_fused<<<(N_NODES + 63) / 64, 256, 0, stream>>>(ybf4, W1frag, W2frag, b1, b2, out);
}